// Round 16
// baseline (1543.649 us; speedup 1.0000x reference)
//
#include <hip/hip_runtime.h>
#include <math.h>

#define T_LEN 32768
#define NCH   16
#define NB    8
#define NWIN  252
#define NBAND 6
#define NPAIR 136
#define NFR   1020   // unique STFT frames needed (max widx = 251*4+15 = 1019)

typedef float v2f __attribute__((ext_vector_type(2)));

// compile-time upper-triangle pair table (p -> (c,d))
struct PairTab { int c[NPAIR]; int d[NPAIR]; };
constexpr PairTab mkpairs() {
    PairTab P{}; int p = 0;
    for (int c = 0; c < 16; ++c)
        for (int d = c; d < 16; ++d) { P.c[p] = c; P.d[p] = d; ++p; }
    return P;
}
constexpr PairTab PT = mkpairs();

// CSD accumulate, 8-wave split (17 pairs, stride 8) — fused-fallback path
template<int G>
__device__ __forceinline__ void acc_csd(const v2f* __restrict__ X,
                                        v2f* __restrict__ acc)
{
#pragma unroll
    for (int t = 0; t < 17; ++t) {
        const int c = PT.c[G + 8 * t];
        const int d = PT.d[G + 8 * t];
        v2f Xc = X[c], Xd = X[d];
        acc[t] = __builtin_elementwise_fma(Xc, Xd.xx, acc[t]);
        acc[t] = __builtin_elementwise_fma((v2f){Xc.y, -Xc.x}, Xd.yy, acc[t]);
    }
}

// CSD accumulate, 16-wave split (8 or 9 pairs, stride 16) — csd2 path
template<int GG>
__device__ __forceinline__ void acc_csd16(const v2f* __restrict__ X,
                                          v2f* __restrict__ acc)
{
    constexpr int NT = (GG < 8) ? 9 : 8;
#pragma unroll
    for (int t = 0; t < NT; ++t) {
        const int c = PT.c[GG + 16 * t];
        const int d = PT.d[GG + 16 * t];
        v2f Xc = X[c], Xd = X[d];
        acc[t] = __builtin_elementwise_fma(Xc, Xd.xx, acc[t]);
        acc[t] = __builtin_elementwise_fma((v2f){Xc.y, -Xc.x}, Xd.yy, acc[t]);
    }
}

// cross-lane exchange helpers (R4/R11/R14-proven set only)
#define SWZ(v, imm)  __int_as_float(__builtin_amdgcn_ds_swizzle(__float_as_int(v), (imm)))
#define DPPQ(v, ctl) __int_as_float(__builtin_amdgcn_mov_dpp(__float_as_int(v), (ctl), 0xF, 0xF, true))

// packed radix-2 DIF butterfly
__device__ __forceinline__ void bfv(v2f& v, v2f p, v2f tw, v2f twn, v2f sg)
{
    v2f t = __builtin_elementwise_fma(sg, v, p);
    v = __builtin_elementwise_fma(t.xx, tw, t.yy * twn);
}
#define BF2(v, EX, TW, TWN, SG) \
    { v2f p_; p_.x = EX(v.x); p_.y = EX(v.y); bfv(v, p_, TW, TWN, SG); }

#define EX32(v) __int_as_float(__builtin_amdgcn_ds_bpermute(bp32, __float_as_int(v)))
#define EX16(v) SWZ(v, 0x401F)
#define EX8(v)  DPPQ(v, 0x128)   // row_ror:8 == lane^8 (R9/R10/R11/R14-verified)
#define EX4(v)  SWZ(v, 0x101F)
#define EX2(v)  DPPQ(v, 0x4E)    // quad_perm [2,3,0,1] = xor2
#define EX1(v)  DPPQ(v, 0xB1)    // quad_perm [1,0,3,2] = xor1

// shared FFT per-lane constant setup (R14 verbatim)
#define FFT_LANE_SETUP                                                        \
    const double PI = 3.14159265358979323846;                                 \
    const float  WI = (float)(1.0 / sqrt(47.625));                            \
    const float wlo = (float)(0.5 - 0.5 * cos(2.0 * PI * (double)lane / 127.0)) * WI;        \
    const float whi = (float)(0.5 - 0.5 * cos(2.0 * PI * (double)(lane + 64) / 127.0)) * WI; \
    const float PIF = 3.14159265358979f;                                      \
    float w128r, w128i;                                                       \
    { float a = -2.f * PIF * (float)lane / 128.f; sincosf(a, &w128i, &w128r); } \
    float t32r, t32i, t16r, t16i, t8r, t8i, t4r, t4i, t2r, t2i;               \
    { float a = (lane & 32) ? -2.f * PIF * (float)(lane & 31) / 64.f : 0.f; sincosf(a, &t32i, &t32r); } \
    { float a = (lane & 16) ? -2.f * PIF * (float)(lane & 15) / 32.f : 0.f; sincosf(a, &t16i, &t16r); } \
    { float a = (lane &  8) ? -2.f * PIF * (float)(lane &  7) / 16.f : 0.f; sincosf(a, &t8i,  &t8r ); } \
    { float a = (lane &  4) ? -2.f * PIF * (float)(lane &  3) /  8.f : 0.f; sincosf(a, &t4i,  &t4r ); } \
    { float a = (lane &  2) ? -2.f * PIF * (float)(lane &  1) /  4.f : 0.f; sincosf(a, &t2i,  &t2r ); } \
    const v2f TWH  = { w128r,  w128i }, TWHN = { -w128i, w128r };             \
    const v2f TW32 = { t32r, t32i },    TW32N = { -t32i, t32r };              \
    const v2f TW16 = { t16r, t16i },    TW16N = { -t16i, t16r };              \
    const v2f TW8  = { t8r,  t8i  },    TW8N  = { -t8i,  t8r  };              \
    const v2f TW4  = { t4r,  t4i  },    TW4N  = { -t4i,  t4r  };              \
    const v2f TW2  = { t2r,  t2i  },    TW2N  = { -t2i,  t2r  };              \
    const v2f SG32 = { (lane & 32) ? -1.f : 1.f, (lane & 32) ? -1.f : 1.f };  \
    const v2f SG16 = { (lane & 16) ? -1.f : 1.f, (lane & 16) ? -1.f : 1.f };  \
    const v2f SG8  = { (lane &  8) ? -1.f : 1.f, (lane &  8) ? -1.f : 1.f };  \
    const v2f SG4  = { (lane &  4) ? -1.f : 1.f, (lane &  4) ? -1.f : 1.f };  \
    const v2f SG2  = { (lane &  2) ? -1.f : 1.f, (lane &  2) ? -1.f : 1.f };  \
    const v2f SG1  = { (lane &  1) ? -1.f : 1.f, (lane &  1) ? -1.f : 1.f };  \
    const int bp32 = 4 * (lane ^ 32);                                         \
    const int La = (int)(__brev((unsigned)(f >> 1)) >> 26);                   \
    const int Lb = (int)(__brev((unsigned)((128 - f) >> 1)) >> 26);           \
    const int pa = f & 1;

// full FFT + untangle body: consumes S0,S1, produces X0,X1 (R14 verbatim)
#define FFT_BODY(S0, S1, X0, X1, scrrow)                                      \
    {                                                                         \
        v2f D = S0 - S1;                                                      \
        S0 = S0 + S1;                                                         \
        S1 = __builtin_elementwise_fma(D.xx, TWH, D.yy * TWHN);               \
    }                                                                         \
    BF2(S0, EX32, TW32, TW32N, SG32)                                          \
    BF2(S1, EX32, TW32, TW32N, SG32)                                          \
    BF2(S0, EX16, TW16, TW16N, SG16)                                          \
    BF2(S1, EX16, TW16, TW16N, SG16)                                          \
    BF2(S0, EX8,  TW8,  TW8N,  SG8)                                           \
    BF2(S1, EX8,  TW8,  TW8N,  SG8)                                           \
    BF2(S0, EX4,  TW4,  TW4N,  SG4)                                           \
    BF2(S1, EX4,  TW4,  TW4N,  SG4)                                           \
    BF2(S0, EX2,  TW2,  TW2N,  SG2)                                           \
    BF2(S1, EX2,  TW2,  TW2N,  SG2)                                           \
    {                                                                         \
        v2f p_; p_.x = EX1(S0.x); p_.y = EX1(S0.y);                           \
        S0 = __builtin_elementwise_fma(SG1, S0, p_);                          \
    }                                                                         \
    {                                                                         \
        v2f p_; p_.x = EX1(S1.x); p_.y = EX1(S1.y);                           \
        S1 = __builtin_elementwise_fma(SG1, S1, p_);                          \
    }                                                                         \
    scrrow[0][lane >> 4][lane & 15] = S0;                                     \
    scrrow[1][lane >> 4][lane & 15] = S1;                                     \
    v2f Ua = scrrow[pa][La >> 4][La & 15];                                    \
    v2f Ub = scrrow[pa][Lb >> 4][Lb & 15];                                    \
    v2f X0 = { 0.5f * (Ua.x + Ub.x), 0.5f * (Ua.y - Ub.y) };                  \
    v2f X1 = { 0.5f * (Ua.y + Ub.y), 0.5f * (Ub.x - Ua.x) };

// ---------------------------------------------------------------------------
// stft_kernel: each wave computes ONE unique frame's packed 2-channel 128-pt
// FFT (channels p, p+8), writes both spectra. Layout: stft[b][fr][ch][bin]
// so csd2's per-frame working set is one contiguous 8 KB slab. Writes stay
// coalesced (contiguous in lane). Zero barriers.
// ---------------------------------------------------------------------------
__global__ __launch_bounds__(512) void stft_kernel(const float* __restrict__ x,
                                                   v2f* __restrict__ stft)
{
    const int tid  = threadIdx.x;
    const int lane = tid & 63;
    const int g    = tid >> 6;
    const int task = blockIdx.x * 8 + g;     // 0..65279
    const int fr   = task % NFR;
    const int pb   = task / NFR;             // 0..63
    const int pair = pb & 7, b = pb >> 3;
    const int f    = lane + 1;

    __shared__ v2f scr[8][2][4][17];         // diag-padded (R14-proven)

    FFT_LANE_SETUP

    const float* xp0 = x + (size_t)(b * NCH + pair) * T_LEN + (size_t)fr * 32;
    const float* xp1 = xp0 + 8 * (size_t)T_LEN;

    v2f S0 = (v2f){ xp0[lane],      xp1[lane]      } * wlo;
    v2f S1 = (v2f){ xp0[lane + 64], xp1[lane + 64] } * whi;

    FFT_BODY(S0, S1, X0, X1, scr[g])

    v2f* fb = stft + ((size_t)(b * NFR + fr) * NCH) * 64 + lane;
    fb[(size_t)pair * 64]       = X0;
    fb[(size_t)(pair + 8) * 64] = X1;
}

// ---------------------------------------------------------------------------
// csd_band_kernel2: one 1024-thread block per (b,w); 16 waves, wave gg owns
// pairs {gg, gg+16, ...}. Reads per-frame 8 KB contiguous slabs (L1-shared by
// all 16 waves, L2-shared by 4 adjacent-w blocks). Register DOUBLE-BUFFER:
// frame j+1's 16 loads issued before accumulating frame j (static unroll-by-2,
// rule-#20-safe). VGPR ~100 < the 128 cliff at 16 waves/CU.
// ---------------------------------------------------------------------------
__global__ __launch_bounds__(1024) void csd_band_kernel2(const v2f* __restrict__ stft,
                                                         float* __restrict__ band)
{
    const int w    = blockIdx.x;
    const int b    = blockIdx.y;
    const int tid  = threadIdx.x;
    const int lane = tid & 63;
    const int gg   = tid >> 6;   // wave 0..15

    __shared__ float bl[NBAND][NPAIR];
    __shared__ unsigned char pc_[NPAIR], pd_[NPAIR];

    for (int i = tid; i < NBAND * NPAIR; i += 1024) (&bl[0][0])[i] = 0.f;
    if (tid < NPAIR) {
        int rem = tid, c = 0;
        while (rem >= 16 - c) { rem -= 16 - c; ++c; }
        pc_[tid] = (unsigned char)c; pd_[tid] = (unsigned char)(c + rem);
    }

    v2f acc[9];
#pragma unroll
    for (int t = 0; t < 9; ++t) acc[t] = (v2f){0.f, 0.f};

    // frame j slab: base + j*NCH*64 ; channel c at +c*64
    const v2f* base = stft + ((size_t)(b * NFR + 4 * w) * NCH) * 64 + lane;

#define LDX(dst, j)                                                   \
    _Pragma("unroll")                                                 \
    for (int c = 0; c < 16; ++c)                                      \
        dst[c] = base[(size_t)((j) * NCH + c) * 64];

#define ACCX(Xv)                                                      \
    switch (gg) {                                                     \
        case 0:  acc_csd16<0>(Xv, acc);  break;                       \
        case 1:  acc_csd16<1>(Xv, acc);  break;                       \
        case 2:  acc_csd16<2>(Xv, acc);  break;                       \
        case 3:  acc_csd16<3>(Xv, acc);  break;                       \
        case 4:  acc_csd16<4>(Xv, acc);  break;                       \
        case 5:  acc_csd16<5>(Xv, acc);  break;                       \
        case 6:  acc_csd16<6>(Xv, acc);  break;                       \
        case 7:  acc_csd16<7>(Xv, acc);  break;                       \
        case 8:  acc_csd16<8>(Xv, acc);  break;                       \
        case 9:  acc_csd16<9>(Xv, acc);  break;                       \
        case 10: acc_csd16<10>(Xv, acc); break;                       \
        case 11: acc_csd16<11>(Xv, acc); break;                       \
        case 12: acc_csd16<12>(Xv, acc); break;                       \
        case 13: acc_csd16<13>(Xv, acc); break;                       \
        case 14: acc_csd16<14>(Xv, acc); break;                       \
        default: acc_csd16<15>(Xv, acc); break;                       \
    }

    __syncthreads();

    v2f Xa[16], Xb[16];
    LDX(Xa, 0)
#pragma unroll 1
    for (int jj = 0; jj < 8; ++jj) {
        const int j0 = 2 * jj;
        LDX(Xb, j0 + 1)         // prefetch odd frame
        ACCX(Xa)                // consume even frame (hides Xb latency)
        if (jj < 7) {
            LDX(Xa, j0 + 2)     // prefetch next even frame
        }
        ACCX(Xb)                // consume odd frame (hides Xa latency)
    }
#undef LDX
#undef ACCX

    // ---- band reduction ----
    const int kband = (lane < 6) ? 0 : (lane < 12) ? 1 : (lane < 19) ? 2
                    : (lane < 32) ? 3 : (lane < 48) ? 4 : 5;
#pragma unroll
    for (int t = 0; t < 9; ++t) {
        int p = gg + 16 * t;
        if (p < NPAIR) {
            float vv = fmaf(acc[t].x, acc[t].x, acc[t].y * acc[t].y);
            atomicAdd(&bl[kband][p], vv);
        }
    }
    __syncthreads();

    const float rs[NBAND] = { 1.f/(256.f*6.f), 1.f/(256.f*6.f), 1.f/(256.f*7.f),
                              1.f/(256.f*13.f), 1.f/(256.f*16.f), 1.f/(256.f*16.f) };
    float* bb = band + (size_t)(b * NWIN + w) * (NBAND * 256);
    for (int i = tid; i < NBAND * NPAIR; i += 1024) {
        int k = i / NPAIR, p = i - k * NPAIR;
        int c = pc_[p], d = pd_[p];
        float val = bl[k][p] * rs[k];
        bb[k * 256 + c * 16 + d] = val;
        bb[k * 256 + d * 16 + c] = val;
    }
}

// ---------------------------------------------------------------------------
// Fallback K1 (R14-proven, 237us): fused STFT+CSD+band, used if ws too small.
// ---------------------------------------------------------------------------
__global__ __launch_bounds__(512, 2) void csd_band_kernel(const float* __restrict__ x,
                                                          float* __restrict__ band)
{
    const int w    = blockIdx.x;
    const int b    = blockIdx.y;
    const int tid  = threadIdx.x;
    const int lane = tid & 63;
    const int g    = tid >> 6;
    const int f    = lane + 1;

    __shared__ v2f  X2[2][NCH][64];
    __shared__ v2f  scr[8][2][4][17];
    __shared__ float bl[NBAND][NPAIR];
    __shared__ unsigned char pc_[NPAIR], pd_[NPAIR];

    for (int i = tid; i < NBAND * NPAIR; i += 512) (&bl[0][0])[i] = 0.f;
    if (tid < NPAIR) {
        int rem = tid, c = 0;
        while (rem >= 16 - c) { rem -= 16 - c; ++c; }
        pc_[tid] = (unsigned char)c; pd_[tid] = (unsigned char)(c + rem);
    }

    FFT_LANE_SETUP

    v2f acc[17];
#pragma unroll
    for (int t = 0; t < 17; ++t) acc[t] = (v2f){0.f, 0.f};

    const float* xp0 = x + (size_t)(b * NCH + g) * T_LEN + (size_t)w * 128;
    const float* xp1 = xp0 + 8 * (size_t)T_LEN;

    __syncthreads();

    for (int s = 0; s < 16; ++s) {
        v2f S0 = (v2f){ xp0[s * 32 + lane],      xp1[s * 32 + lane]      } * wlo;
        v2f S1 = (v2f){ xp0[s * 32 + lane + 64], xp1[s * 32 + lane + 64] } * whi;

        FFT_BODY(S0, S1, X0, X1, scr[g])

        const int pp = s & 1;
        X2[pp][g][lane]     = X0;
        X2[pp][g + 8][lane] = X1;
        __syncthreads();

        v2f X[16];
#pragma unroll
        for (int c = 0; c < 16; ++c) X[c] = X2[pp][c][lane];
        switch (g) {
            case 0: acc_csd<0>(X, acc); break;
            case 1: acc_csd<1>(X, acc); break;
            case 2: acc_csd<2>(X, acc); break;
            case 3: acc_csd<3>(X, acc); break;
            case 4: acc_csd<4>(X, acc); break;
            case 5: acc_csd<5>(X, acc); break;
            case 6: acc_csd<6>(X, acc); break;
            default: acc_csd<7>(X, acc); break;
        }
    }

    const int kband = (lane < 6) ? 0 : (lane < 12) ? 1 : (lane < 19) ? 2
                    : (lane < 32) ? 3 : (lane < 48) ? 4 : 5;
#pragma unroll
    for (int t = 0; t < 17; ++t) {
        float vv = fmaf(acc[t].x, acc[t].x, acc[t].y * acc[t].y);
        atomicAdd(&bl[kband][g + 8 * t], vv);
    }
    __syncthreads();

    const float rs[NBAND] = { 1.f/(256.f*6.f), 1.f/(256.f*6.f), 1.f/(256.f*7.f),
                              1.f/(256.f*13.f), 1.f/(256.f*16.f), 1.f/(256.f*16.f) };
    float* bb = band + (size_t)(b * NWIN + w) * (NBAND * 256);
    for (int i = tid; i < NBAND * NPAIR; i += 512) {
        int k = i / NPAIR, p = i - k * NPAIR;
        int c = pc_[p], d = pd_[p];
        float val = bl[k][p] * rs[k];
        bb[k * 256 + c * 16 + d] = val;
        bb[k * 256 + d * 16 + c] = val;
    }
}

// ---------------------------------------------------------------------------
// Kernel 2: 16x16 symmetric eig (fp32 parallel Jacobi, tournament, 4 sweeps).
// 8 matrices per 512-thread block, one wave each, zero barriers. [proven]
// ---------------------------------------------------------------------------
__device__ __forceinline__ void tourney(int rr, int j, int& p, int& q)
{
    if (j == 0) { p = 15; q = rr; }
    else { p = (rr + j) % 15; q = (rr + 15 - j) % 15; }
    if (p > q) { int t_ = p; p = q; q = t_; }
}

__global__ __launch_bounds__(512) void eig_log_kernel(const float* __restrict__ band,
                                                      float* __restrict__ out)
{
    const int tid  = threadIdx.x;
    const int g    = tid >> 6;
    const int lane = tid & 63;
    const int m    = blockIdx.x * 8 + g;
    const int k    = m % NBAND;
    const int bw   = m / NBAND;
    const int w    = bw % NWIN;
    const int b    = bw / NWIN;
    const int j    = lane >> 3;
    const int n2   = lane & 7;

    __shared__ float A[8][16][18];
    __shared__ float DT[8][16][18];
    __shared__ float VT[8][16][18];
    __shared__ float lv[8][16];

    const float* M = band + ((size_t)(b * NWIN + w) * NBAND + k) * 256;
#pragma unroll
    for (int it = 0; it < 4; ++it) {
        int i = lane + it * 64, r = i >> 4, c = i & 15;
        A[g][r][c]  = M[i];
        VT[g][r][c] = (r == c) ? 1.f : 0.f;
    }

    for (int sweep = 0; sweep < 4; ++sweep) {
        for (int rr = 0; rr < 15; ++rr) {
            int p, q; tourney(rr, j, p, q);
            float app = A[g][p][p], aqq = A[g][q][q], apq = A[g][p][q];
            float c_ = 1.f, s_ = 0.f;
            if (apq != 0.f) {
                float tau = (aqq - app) / (2.f * apq);
                float t   = copysignf(1.f, tau) / (fabsf(tau) + sqrtf(1.f + tau * tau));
                c_ = 1.f / sqrtf(1.f + t * t);
                s_ = t * c_;
            }
            float2 ap = *(const float2*)&A[g][p][2 * n2];
            float2 aq = *(const float2*)&A[g][q][2 * n2];
            DT[g][2 * n2][p]     = c_ * ap.x - s_ * aq.x;
            DT[g][2 * n2 + 1][p] = c_ * ap.y - s_ * aq.y;
            DT[g][2 * n2][q]     = s_ * ap.x + c_ * aq.x;
            DT[g][2 * n2 + 1][q] = s_ * ap.y + c_ * aq.y;

            float2 dp = *(const float2*)&DT[g][p][2 * n2];
            float2 dq = *(const float2*)&DT[g][q][2 * n2];
            *(float2*)&A[g][p][2 * n2] = make_float2(c_ * dp.x - s_ * dq.x,
                                                     c_ * dp.y - s_ * dq.y);
            *(float2*)&A[g][q][2 * n2] = make_float2(s_ * dp.x + c_ * dq.x,
                                                     s_ * dp.y + c_ * dq.y);
            float2 vp = *(const float2*)&VT[g][p][2 * n2];
            float2 vq = *(const float2*)&VT[g][q][2 * n2];
            *(float2*)&VT[g][p][2 * n2] = make_float2(c_ * vp.x - s_ * vq.x,
                                                      c_ * vp.y - s_ * vq.y);
            *(float2*)&VT[g][q][2 * n2] = make_float2(s_ * vp.x + c_ * vq.x,
                                                      s_ * vp.y + c_ * vq.y);
        }
    }

    if (lane < 16) {
        float l = logf(A[g][lane][lane]);
        if (isnan(l) || isinf(l)) l = 0.f;
        lv[g][lane] = l;
    }

    float* ob = out + (size_t)(b * NBAND + k) * 256 * NWIN;
#pragma unroll
    for (int it = 0; it < 4; ++it) {
        int i = lane + it * 64, c = i >> 4, d = i & 15;
        float sum = 0.f;
#pragma unroll
        for (int e = 0; e < 16; ++e) sum = fmaf(VT[g][e][c] * lv[g][e], VT[g][e][d], sum);
        ob[(size_t)i * NWIN + w] = sum;
    }
}

// ---------------------------------------------------------------------------
extern "C" void kernel_launch(void* const* d_in, const int* in_sizes, int n_in,
                              void* d_out, int out_size, void* d_ws, size_t ws_size,
                              hipStream_t stream)
{
    const float* x    = (const float*)d_in[0];
    float*       out  = (float*)d_out;
    float*       band = (float*)d_ws;

    const size_t BAND_BYTES = (size_t)NB * NWIN * NBAND * 256 * 4;      // 12,386,304
    const size_t STFT_BYTES = (size_t)NB * NFR * NCH * 64 * 8;          // 66,846,720

    if (ws_size >= BAND_BYTES + STFT_BYTES) {
        v2f* stft = (v2f*)((char*)d_ws + BAND_BYTES);
        hipLaunchKernelGGL(stft_kernel, dim3(NB * 8 * NFR / 8), dim3(512), 0, stream,
                           x, stft);
        hipLaunchKernelGGL(csd_band_kernel2, dim3(NWIN, NB), dim3(1024), 0, stream,
                           stft, band);
    } else {
        hipLaunchKernelGGL(csd_band_kernel, dim3(NWIN, NB), dim3(512), 0, stream,
                           x, band);
    }

    dim3 g2(NB * NWIN * NBAND / 8), b2(512);
    hipLaunchKernelGGL(eig_log_kernel, g2, b2, 0, stream, band, out);
}

// Round 17
// 448.568 us; speedup vs baseline: 3.4413x; 3.4413x over previous
//
#include <hip/hip_runtime.h>
#include <math.h>

#define T_LEN 32768
#define NCH   16
#define NB    8
#define NWIN  252
#define NBAND 6
#define NPAIR 136
#define NFR   1020   // unique STFT frames needed (max widx = 251*4+15 = 1019)

typedef float v2f __attribute__((ext_vector_type(2)));

// compile-time upper-triangle pair table (p -> (c,d))
struct PairTab { int c[NPAIR]; int d[NPAIR]; };
constexpr PairTab mkpairs() {
    PairTab P{}; int p = 0;
    for (int c = 0; c < 16; ++c)
        for (int d = c; d < 16; ++d) { P.c[p] = c; P.d[p] = d; ++p; }
    return P;
}
constexpr PairTab PT = mkpairs();

// CSD accumulate, 8-wave split (17 pairs, stride 8) — fused-fallback path
template<int G>
__device__ __forceinline__ void acc_csd(const v2f* __restrict__ X,
                                        v2f* __restrict__ acc)
{
#pragma unroll
    for (int t = 0; t < 17; ++t) {
        const int c = PT.c[G + 8 * t];
        const int d = PT.d[G + 8 * t];
        v2f Xc = X[c], Xd = X[d];
        acc[t] = __builtin_elementwise_fma(Xc, Xd.xx, acc[t]);
        acc[t] = __builtin_elementwise_fma((v2f){Xc.y, -Xc.x}, Xd.yy, acc[t]);
    }
}

// CSD accumulate, 16-wave split (8 or 9 pairs, stride 16) — csd2 path
template<int GG>
__device__ __forceinline__ void acc_csd16(const v2f* __restrict__ X,
                                          v2f* __restrict__ acc)
{
    constexpr int NT = (GG < 8) ? 9 : 8;
#pragma unroll
    for (int t = 0; t < NT; ++t) {
        const int c = PT.c[GG + 16 * t];
        const int d = PT.d[GG + 16 * t];
        v2f Xc = X[c], Xd = X[d];
        acc[t] = __builtin_elementwise_fma(Xc, Xd.xx, acc[t]);
        acc[t] = __builtin_elementwise_fma((v2f){Xc.y, -Xc.x}, Xd.yy, acc[t]);
    }
}

// cross-lane exchange helpers (R4/R11/R14-proven set only)
#define SWZ(v, imm)  __int_as_float(__builtin_amdgcn_ds_swizzle(__float_as_int(v), (imm)))
#define DPPQ(v, ctl) __int_as_float(__builtin_amdgcn_mov_dpp(__float_as_int(v), (ctl), 0xF, 0xF, true))

// packed radix-2 DIF butterfly
__device__ __forceinline__ void bfv(v2f& v, v2f p, v2f tw, v2f twn, v2f sg)
{
    v2f t = __builtin_elementwise_fma(sg, v, p);
    v = __builtin_elementwise_fma(t.xx, tw, t.yy * twn);
}
#define BF2(v, EX, TW, TWN, SG) \
    { v2f p_; p_.x = EX(v.x); p_.y = EX(v.y); bfv(v, p_, TW, TWN, SG); }

#define EX32(v) __int_as_float(__builtin_amdgcn_ds_bpermute(bp32, __float_as_int(v)))
#define EX16(v) SWZ(v, 0x401F)
#define EX8(v)  DPPQ(v, 0x128)   // row_ror:8 == lane^8 (R9/R10/R11/R14-verified)
#define EX4(v)  SWZ(v, 0x101F)
#define EX2(v)  DPPQ(v, 0x4E)    // quad_perm [2,3,0,1] = xor2
#define EX1(v)  DPPQ(v, 0xB1)    // quad_perm [1,0,3,2] = xor1

// shared FFT per-lane constant setup (R14 verbatim)
#define FFT_LANE_SETUP                                                        \
    const double PI = 3.14159265358979323846;                                 \
    const float  WI = (float)(1.0 / sqrt(47.625));                            \
    const float wlo = (float)(0.5 - 0.5 * cos(2.0 * PI * (double)lane / 127.0)) * WI;        \
    const float whi = (float)(0.5 - 0.5 * cos(2.0 * PI * (double)(lane + 64) / 127.0)) * WI; \
    const float PIF = 3.14159265358979f;                                      \
    float w128r, w128i;                                                       \
    { float a = -2.f * PIF * (float)lane / 128.f; sincosf(a, &w128i, &w128r); } \
    float t32r, t32i, t16r, t16i, t8r, t8i, t4r, t4i, t2r, t2i;               \
    { float a = (lane & 32) ? -2.f * PIF * (float)(lane & 31) / 64.f : 0.f; sincosf(a, &t32i, &t32r); } \
    { float a = (lane & 16) ? -2.f * PIF * (float)(lane & 15) / 32.f : 0.f; sincosf(a, &t16i, &t16r); } \
    { float a = (lane &  8) ? -2.f * PIF * (float)(lane &  7) / 16.f : 0.f; sincosf(a, &t8i,  &t8r ); } \
    { float a = (lane &  4) ? -2.f * PIF * (float)(lane &  3) /  8.f : 0.f; sincosf(a, &t4i,  &t4r ); } \
    { float a = (lane &  2) ? -2.f * PIF * (float)(lane &  1) /  4.f : 0.f; sincosf(a, &t2i,  &t2r ); } \
    const v2f TWH  = { w128r,  w128i }, TWHN = { -w128i, w128r };             \
    const v2f TW32 = { t32r, t32i },    TW32N = { -t32i, t32r };              \
    const v2f TW16 = { t16r, t16i },    TW16N = { -t16i, t16r };              \
    const v2f TW8  = { t8r,  t8i  },    TW8N  = { -t8i,  t8r  };              \
    const v2f TW4  = { t4r,  t4i  },    TW4N  = { -t4i,  t4r  };              \
    const v2f TW2  = { t2r,  t2i  },    TW2N  = { -t2i,  t2r  };              \
    const v2f SG32 = { (lane & 32) ? -1.f : 1.f, (lane & 32) ? -1.f : 1.f };  \
    const v2f SG16 = { (lane & 16) ? -1.f : 1.f, (lane & 16) ? -1.f : 1.f };  \
    const v2f SG8  = { (lane &  8) ? -1.f : 1.f, (lane &  8) ? -1.f : 1.f };  \
    const v2f SG4  = { (lane &  4) ? -1.f : 1.f, (lane &  4) ? -1.f : 1.f };  \
    const v2f SG2  = { (lane &  2) ? -1.f : 1.f, (lane &  2) ? -1.f : 1.f };  \
    const v2f SG1  = { (lane &  1) ? -1.f : 1.f, (lane &  1) ? -1.f : 1.f };  \
    const int bp32 = 4 * (lane ^ 32);                                         \
    const int La = (int)(__brev((unsigned)(f >> 1)) >> 26);                   \
    const int Lb = (int)(__brev((unsigned)((128 - f) >> 1)) >> 26);           \
    const int pa = f & 1;

// full FFT + untangle body: consumes S0,S1, produces X0,X1 (R14 verbatim)
#define FFT_BODY(S0, S1, X0, X1, scrrow)                                      \
    {                                                                         \
        v2f D = S0 - S1;                                                      \
        S0 = S0 + S1;                                                         \
        S1 = __builtin_elementwise_fma(D.xx, TWH, D.yy * TWHN);               \
    }                                                                         \
    BF2(S0, EX32, TW32, TW32N, SG32)                                          \
    BF2(S1, EX32, TW32, TW32N, SG32)                                          \
    BF2(S0, EX16, TW16, TW16N, SG16)                                          \
    BF2(S1, EX16, TW16, TW16N, SG16)                                          \
    BF2(S0, EX8,  TW8,  TW8N,  SG8)                                           \
    BF2(S1, EX8,  TW8,  TW8N,  SG8)                                           \
    BF2(S0, EX4,  TW4,  TW4N,  SG4)                                           \
    BF2(S1, EX4,  TW4,  TW4N,  SG4)                                           \
    BF2(S0, EX2,  TW2,  TW2N,  SG2)                                           \
    BF2(S1, EX2,  TW2,  TW2N,  SG2)                                           \
    {                                                                         \
        v2f p_; p_.x = EX1(S0.x); p_.y = EX1(S0.y);                           \
        S0 = __builtin_elementwise_fma(SG1, S0, p_);                          \
    }                                                                         \
    {                                                                         \
        v2f p_; p_.x = EX1(S1.x); p_.y = EX1(S1.y);                           \
        S1 = __builtin_elementwise_fma(SG1, S1, p_);                          \
    }                                                                         \
    scrrow[0][lane >> 4][lane & 15] = S0;                                     \
    scrrow[1][lane >> 4][lane & 15] = S1;                                     \
    v2f Ua = scrrow[pa][La >> 4][La & 15];                                    \
    v2f Ub = scrrow[pa][Lb >> 4][Lb & 15];                                    \
    v2f X0 = { 0.5f * (Ua.x + Ub.x), 0.5f * (Ua.y - Ub.y) };                  \
    v2f X1 = { 0.5f * (Ua.y + Ub.y), 0.5f * (Ub.x - Ua.x) };

// ---------------------------------------------------------------------------
// stft_kernel: each wave computes ONE unique frame's packed 2-channel 128-pt
// FFT (channels p, p+8), writes both spectra. Layout: stft[b][fr][ch][bin]
// so csd2's per-frame working set is one contiguous 8 KB slab. Zero barriers.
// ---------------------------------------------------------------------------
__global__ __launch_bounds__(512) void stft_kernel(const float* __restrict__ x,
                                                   v2f* __restrict__ stft)
{
    const int tid  = threadIdx.x;
    const int lane = tid & 63;
    const int g    = tid >> 6;
    const int task = blockIdx.x * 8 + g;     // 0..65279
    const int fr   = task % NFR;
    const int pb   = task / NFR;             // 0..63
    const int pair = pb & 7, b = pb >> 3;
    const int f    = lane + 1;

    __shared__ v2f scr[8][2][4][17];         // diag-padded (R14-proven)

    FFT_LANE_SETUP

    const float* xp0 = x + (size_t)(b * NCH + pair) * T_LEN + (size_t)fr * 32;
    const float* xp1 = xp0 + 8 * (size_t)T_LEN;

    v2f S0 = (v2f){ xp0[lane],      xp1[lane]      } * wlo;
    v2f S1 = (v2f){ xp0[lane + 64], xp1[lane + 64] } * whi;

    FFT_BODY(S0, S1, X0, X1, scr[g])

    v2f* fb = stft + ((size_t)(b * NFR + fr) * NCH) * 64 + lane;
    fb[(size_t)pair * 64]       = X0;
    fb[(size_t)(pair + 8) * 64] = X1;
}

// ---------------------------------------------------------------------------
// csd_band_kernel2: one 1024-thread block per (b,w); 16 waves, wave gg owns
// pairs {gg, gg+16, ...}. Per frame all 16 waves read the SAME contiguous
// 8 KB slab (L1-broadcast; 4 w-adjacent blocks share via L2). R15's proven
// no-spill loop body; __launch_bounds__(1024,4) claims the full 128-VGPR
// budget of a single-resident 1024-thr block (R16's spill was the default
// 64-VGPR cap); #pragma unroll 2 gives compiler-scheduled cross-iter ILP
// with static X[16] indices (rule-#20-safe).
// ---------------------------------------------------------------------------
__global__ __launch_bounds__(1024, 4) void csd_band_kernel2(const v2f* __restrict__ stft,
                                                            float* __restrict__ band)
{
    const int w    = blockIdx.x;
    const int b    = blockIdx.y;
    const int tid  = threadIdx.x;
    const int lane = tid & 63;
    const int gg   = tid >> 6;   // wave 0..15

    __shared__ float bl[NBAND][NPAIR];
    __shared__ unsigned char pc_[NPAIR], pd_[NPAIR];

    for (int i = tid; i < NBAND * NPAIR; i += 1024) (&bl[0][0])[i] = 0.f;
    if (tid < NPAIR) {
        int rem = tid, c = 0;
        while (rem >= 16 - c) { rem -= 16 - c; ++c; }
        pc_[tid] = (unsigned char)c; pd_[tid] = (unsigned char)(c + rem);
    }

    v2f acc[9];
#pragma unroll
    for (int t = 0; t < 9; ++t) acc[t] = (v2f){0.f, 0.f};

    // frame j slab: base + j*NCH*64 ; channel c at +c*64
    const v2f* base = stft + ((size_t)(b * NFR + 4 * w) * NCH) * 64 + lane;

    __syncthreads();

#pragma unroll 2
    for (int j = 0; j < 16; ++j) {
        v2f X[16];
#pragma unroll
        for (int c = 0; c < 16; ++c)
            X[c] = base[(size_t)(j * NCH + c) * 64];
        switch (gg) {
            case 0:  acc_csd16<0>(X, acc);  break;
            case 1:  acc_csd16<1>(X, acc);  break;
            case 2:  acc_csd16<2>(X, acc);  break;
            case 3:  acc_csd16<3>(X, acc);  break;
            case 4:  acc_csd16<4>(X, acc);  break;
            case 5:  acc_csd16<5>(X, acc);  break;
            case 6:  acc_csd16<6>(X, acc);  break;
            case 7:  acc_csd16<7>(X, acc);  break;
            case 8:  acc_csd16<8>(X, acc);  break;
            case 9:  acc_csd16<9>(X, acc);  break;
            case 10: acc_csd16<10>(X, acc); break;
            case 11: acc_csd16<11>(X, acc); break;
            case 12: acc_csd16<12>(X, acc); break;
            case 13: acc_csd16<13>(X, acc); break;
            case 14: acc_csd16<14>(X, acc); break;
            default: acc_csd16<15>(X, acc); break;
        }
    }

    // ---- band reduction ----
    const int kband = (lane < 6) ? 0 : (lane < 12) ? 1 : (lane < 19) ? 2
                    : (lane < 32) ? 3 : (lane < 48) ? 4 : 5;
#pragma unroll
    for (int t = 0; t < 9; ++t) {
        int p = gg + 16 * t;
        if (p < NPAIR) {
            float vv = fmaf(acc[t].x, acc[t].x, acc[t].y * acc[t].y);
            atomicAdd(&bl[kband][p], vv);
        }
    }
    __syncthreads();

    const float rs[NBAND] = { 1.f/(256.f*6.f), 1.f/(256.f*6.f), 1.f/(256.f*7.f),
                              1.f/(256.f*13.f), 1.f/(256.f*16.f), 1.f/(256.f*16.f) };
    float* bb = band + (size_t)(b * NWIN + w) * (NBAND * 256);
    for (int i = tid; i < NBAND * NPAIR; i += 1024) {
        int k = i / NPAIR, p = i - k * NPAIR;
        int c = pc_[p], d = pd_[p];
        float val = bl[k][p] * rs[k];
        bb[k * 256 + c * 16 + d] = val;
        bb[k * 256 + d * 16 + c] = val;
    }
}

// ---------------------------------------------------------------------------
// Fallback K1 (R14-proven, 237us): fused STFT+CSD+band, used if ws too small.
// ---------------------------------------------------------------------------
__global__ __launch_bounds__(512, 2) void csd_band_kernel(const float* __restrict__ x,
                                                          float* __restrict__ band)
{
    const int w    = blockIdx.x;
    const int b    = blockIdx.y;
    const int tid  = threadIdx.x;
    const int lane = tid & 63;
    const int g    = tid >> 6;
    const int f    = lane + 1;

    __shared__ v2f  X2[2][NCH][64];
    __shared__ v2f  scr[8][2][4][17];
    __shared__ float bl[NBAND][NPAIR];
    __shared__ unsigned char pc_[NPAIR], pd_[NPAIR];

    for (int i = tid; i < NBAND * NPAIR; i += 512) (&bl[0][0])[i] = 0.f;
    if (tid < NPAIR) {
        int rem = tid, c = 0;
        while (rem >= 16 - c) { rem -= 16 - c; ++c; }
        pc_[tid] = (unsigned char)c; pd_[tid] = (unsigned char)(c + rem);
    }

    FFT_LANE_SETUP

    v2f acc[17];
#pragma unroll
    for (int t = 0; t < 17; ++t) acc[t] = (v2f){0.f, 0.f};

    const float* xp0 = x + (size_t)(b * NCH + g) * T_LEN + (size_t)w * 128;
    const float* xp1 = xp0 + 8 * (size_t)T_LEN;

    __syncthreads();

    for (int s = 0; s < 16; ++s) {
        v2f S0 = (v2f){ xp0[s * 32 + lane],      xp1[s * 32 + lane]      } * wlo;
        v2f S1 = (v2f){ xp0[s * 32 + lane + 64], xp1[s * 32 + lane + 64] } * whi;

        FFT_BODY(S0, S1, X0, X1, scr[g])

        const int pp = s & 1;
        X2[pp][g][lane]     = X0;
        X2[pp][g + 8][lane] = X1;
        __syncthreads();

        v2f X[16];
#pragma unroll
        for (int c = 0; c < 16; ++c) X[c] = X2[pp][c][lane];
        switch (g) {
            case 0: acc_csd<0>(X, acc); break;
            case 1: acc_csd<1>(X, acc); break;
            case 2: acc_csd<2>(X, acc); break;
            case 3: acc_csd<3>(X, acc); break;
            case 4: acc_csd<4>(X, acc); break;
            case 5: acc_csd<5>(X, acc); break;
            case 6: acc_csd<6>(X, acc); break;
            default: acc_csd<7>(X, acc); break;
        }
    }

    const int kband = (lane < 6) ? 0 : (lane < 12) ? 1 : (lane < 19) ? 2
                    : (lane < 32) ? 3 : (lane < 48) ? 4 : 5;
#pragma unroll
    for (int t = 0; t < 17; ++t) {
        float vv = fmaf(acc[t].x, acc[t].x, acc[t].y * acc[t].y);
        atomicAdd(&bl[kband][g + 8 * t], vv);
    }
    __syncthreads();

    const float rs[NBAND] = { 1.f/(256.f*6.f), 1.f/(256.f*6.f), 1.f/(256.f*7.f),
                              1.f/(256.f*13.f), 1.f/(256.f*16.f), 1.f/(256.f*16.f) };
    float* bb = band + (size_t)(b * NWIN + w) * (NBAND * 256);
    for (int i = tid; i < NBAND * NPAIR; i += 512) {
        int k = i / NPAIR, p = i - k * NPAIR;
        int c = pc_[p], d = pd_[p];
        float val = bl[k][p] * rs[k];
        bb[k * 256 + c * 16 + d] = val;
        bb[k * 256 + d * 16 + c] = val;
    }
}

// ---------------------------------------------------------------------------
// Kernel 2: 16x16 symmetric eig (fp32 parallel Jacobi, tournament, 4 sweeps).
// 8 matrices per 512-thread block, one wave each, zero barriers. [proven]
// ---------------------------------------------------------------------------
__device__ __forceinline__ void tourney(int rr, int j, int& p, int& q)
{
    if (j == 0) { p = 15; q = rr; }
    else { p = (rr + j) % 15; q = (rr + 15 - j) % 15; }
    if (p > q) { int t_ = p; p = q; q = t_; }
}

__global__ __launch_bounds__(512) void eig_log_kernel(const float* __restrict__ band,
                                                      float* __restrict__ out)
{
    const int tid  = threadIdx.x;
    const int g    = tid >> 6;
    const int lane = tid & 63;
    const int m    = blockIdx.x * 8 + g;
    const int k    = m % NBAND;
    const int bw   = m / NBAND;
    const int w    = bw % NWIN;
    const int b    = bw / NWIN;
    const int j    = lane >> 3;
    const int n2   = lane & 7;

    __shared__ float A[8][16][18];
    __shared__ float DT[8][16][18];
    __shared__ float VT[8][16][18];
    __shared__ float lv[8][16];

    const float* M = band + ((size_t)(b * NWIN + w) * NBAND + k) * 256;
#pragma unroll
    for (int it = 0; it < 4; ++it) {
        int i = lane + it * 64, r = i >> 4, c = i & 15;
        A[g][r][c]  = M[i];
        VT[g][r][c] = (r == c) ? 1.f : 0.f;
    }

    for (int sweep = 0; sweep < 4; ++sweep) {
        for (int rr = 0; rr < 15; ++rr) {
            int p, q; tourney(rr, j, p, q);
            float app = A[g][p][p], aqq = A[g][q][q], apq = A[g][p][q];
            float c_ = 1.f, s_ = 0.f;
            if (apq != 0.f) {
                float tau = (aqq - app) / (2.f * apq);
                float t   = copysignf(1.f, tau) / (fabsf(tau) + sqrtf(1.f + tau * tau));
                c_ = 1.f / sqrtf(1.f + t * t);
                s_ = t * c_;
            }
            float2 ap = *(const float2*)&A[g][p][2 * n2];
            float2 aq = *(const float2*)&A[g][q][2 * n2];
            DT[g][2 * n2][p]     = c_ * ap.x - s_ * aq.x;
            DT[g][2 * n2 + 1][p] = c_ * ap.y - s_ * aq.y;
            DT[g][2 * n2][q]     = s_ * ap.x + c_ * aq.x;
            DT[g][2 * n2 + 1][q] = s_ * ap.y + c_ * aq.y;

            float2 dp = *(const float2*)&DT[g][p][2 * n2];
            float2 dq = *(const float2*)&DT[g][q][2 * n2];
            *(float2*)&A[g][p][2 * n2] = make_float2(c_ * dp.x - s_ * dq.x,
                                                     c_ * dp.y - s_ * dq.y);
            *(float2*)&A[g][q][2 * n2] = make_float2(s_ * dp.x + c_ * dq.x,
                                                     s_ * dp.y + c_ * dq.y);
            float2 vp = *(const float2*)&VT[g][p][2 * n2];
            float2 vq = *(const float2*)&VT[g][q][2 * n2];
            *(float2*)&VT[g][p][2 * n2] = make_float2(c_ * vp.x - s_ * vq.x,
                                                      c_ * vp.y - s_ * vq.y);
            *(float2*)&VT[g][q][2 * n2] = make_float2(s_ * vp.x + c_ * vq.x,
                                                      s_ * vp.y + c_ * vq.y);
        }
    }

    if (lane < 16) {
        float l = logf(A[g][lane][lane]);
        if (isnan(l) || isinf(l)) l = 0.f;
        lv[g][lane] = l;
    }

    float* ob = out + (size_t)(b * NBAND + k) * 256 * NWIN;
#pragma unroll
    for (int it = 0; it < 4; ++it) {
        int i = lane + it * 64, c = i >> 4, d = i & 15;
        float sum = 0.f;
#pragma unroll
        for (int e = 0; e < 16; ++e) sum = fmaf(VT[g][e][c] * lv[g][e], VT[g][e][d], sum);
        ob[(size_t)i * NWIN + w] = sum;
    }
}

// ---------------------------------------------------------------------------
extern "C" void kernel_launch(void* const* d_in, const int* in_sizes, int n_in,
                              void* d_out, int out_size, void* d_ws, size_t ws_size,
                              hipStream_t stream)
{
    const float* x    = (const float*)d_in[0];
    float*       out  = (float*)d_out;
    float*       band = (float*)d_ws;

    const size_t BAND_BYTES = (size_t)NB * NWIN * NBAND * 256 * 4;      // 12,386,304
    const size_t STFT_BYTES = (size_t)NB * NFR * NCH * 64 * 8;          // 66,846,720

    if (ws_size >= BAND_BYTES + STFT_BYTES) {
        v2f* stft = (v2f*)((char*)d_ws + BAND_BYTES);
        hipLaunchKernelGGL(stft_kernel, dim3(NB * 8 * NFR / 8), dim3(512), 0, stream,
                           x, stft);
        hipLaunchKernelGGL(csd_band_kernel2, dim3(NWIN, NB), dim3(1024), 0, stream,
                           stft, band);
    } else {
        hipLaunchKernelGGL(csd_band_kernel, dim3(NWIN, NB), dim3(512), 0, stream,
                           x, band);
    }

    dim3 g2(NB * NWIN * NBAND / 8), b2(512);
    hipLaunchKernelGGL(eig_log_kernel, g2, b2, 0, stream, band, out);
}

// Round 18
// 423.680 us; speedup vs baseline: 3.6434x; 1.0587x over previous
//
#include <hip/hip_runtime.h>
#include <math.h>

#define T_LEN 32768
#define NCH   16
#define NB    8
#define NWIN  252
#define NBAND 6
#define NPAIR 136

typedef float v2f __attribute__((ext_vector_type(2)));

// compile-time upper-triangle pair table (p -> (c,d))
struct PairTab { int c[NPAIR]; int d[NPAIR]; };
constexpr PairTab mkpairs() {
    PairTab P{}; int p = 0;
    for (int c = 0; c < 16; ++c)
        for (int d = c; d < 16; ++d) { P.c[p] = c; P.d[p] = d; ++p; }
    return P;
}
constexpr PairTab PT = mkpairs();

// CSD accumulate for wave-group G: pairs {G, G+8, ..., G+128} (17 pairs).
template<int G>
__device__ __forceinline__ void acc_csd(const v2f* __restrict__ X,
                                        v2f* __restrict__ acc)
{
#pragma unroll
    for (int t = 0; t < 17; ++t) {
        const int c = PT.c[G + 8 * t];
        const int d = PT.d[G + 8 * t];
        v2f Xc = X[c], Xd = X[d];
        acc[t] = __builtin_elementwise_fma(Xc, Xd.xx, acc[t]);
        acc[t] = __builtin_elementwise_fma((v2f){Xc.y, -Xc.x}, Xd.yy, acc[t]);
    }
}

// cross-lane exchange helpers (R4/R11/R14-proven set only)
#define SWZ(v, imm)  __int_as_float(__builtin_amdgcn_ds_swizzle(__float_as_int(v), (imm)))
#define DPPQ(v, ctl) __int_as_float(__builtin_amdgcn_mov_dpp(__float_as_int(v), (ctl), 0xF, 0xF, true))

// packed radix-2 DIF butterfly
__device__ __forceinline__ void bfv(v2f& v, v2f p, v2f tw, v2f twn, v2f sg)
{
    v2f t = __builtin_elementwise_fma(sg, v, p);
    v = __builtin_elementwise_fma(t.xx, tw, t.yy * twn);
}
#define BF2(v, EX, TW, TWN, SG) \
    { v2f p_; p_.x = EX(v.x); p_.y = EX(v.y); bfv(v, p_, TW, TWN, SG); }

#define EX32(v) __int_as_float(__builtin_amdgcn_ds_bpermute(bp32, __float_as_int(v)))
#define EX16(v) SWZ(v, 0x401F)
#define EX8(v)  DPPQ(v, 0x128)   // row_ror:8 == lane^8 (R9/R10/R11/R14-verified)
#define EX4(v)  SWZ(v, 0x101F)
#define EX2(v)  DPPQ(v, 0x4E)    // quad_perm [2,3,0,1] = xor2
#define EX1(v)  DPPQ(v, 0xB1)    // quad_perm [1,0,3,2] = xor1

__device__ __forceinline__ void tourney(int rr, int j, int& p, int& q)
{
    if (j == 0) { p = 15; q = rr; }
    else { p = (rr + j) % 15; q = (rr + 15 - j) % 15; }
    if (p > q) { int t_ = p; p = q; q = t_; }
}

// ---------------------------------------------------------------------------
// Fused kernel: STFT + CSD + band averaging + 16x16 eig + log-recompose.
// One 512-thread block per (b,w). Phase 1 = R14's proven CSD pipeline
// (single-barrier ping-pong, VGPR=64). Phase 2: waves 0-5 each run the
// R5/R14-proven wave-synchronous fp32 Jacobi (4 sweeps) on one band matrix,
// reading it straight from bl in LDS (pair-index inverse), writing out
// directly. A/DT/VT alias the dead X2/scr region (21.1 <= 25.1 KB).
// No band workspace, no second CSD kernel, eig overlaps other blocks' CSD.
// ---------------------------------------------------------------------------
__global__ __launch_bounds__(512, 2) void csd_eig_kernel(const float* __restrict__ x,
                                                         float* __restrict__ out)
{
    const int w    = blockIdx.x;
    const int b    = blockIdx.y;
    const int tid  = threadIdx.x;
    const int lane = tid & 63;
    const int g    = tid >> 6;     // wave id 0..7
    const int f    = lane + 1;     // this lane's output bin (1..64)

    // phase-aliased LDS: phase1 = X2(16384) + scr(8704) = 25088 bytes
    //                    phase2 = A+DT+VT (3*6912) + lv(384) = 21120 bytes
    __shared__ __align__(16) char shraw[25088];
    v2f  (*X2)[NCH][64]  = (v2f (*)[NCH][64])shraw;            // [2][16][64]
    v2f  (*scr)[2][4][17] = (v2f (*)[2][4][17])(shraw + 16384); // [8][2][4][17]
    float (*A_)[16][18]  = (float (*)[16][18])shraw;            // [6][16][18]
    float (*DT_)[16][18] = (float (*)[16][18])(shraw + 6912);
    float (*VT_)[16][18] = (float (*)[16][18])(shraw + 13824);
    float (*lv_)[16]     = (float (*)[16])(shraw + 20736);

    __shared__ float bl[NBAND][NPAIR];  // band |csd|^2 sums (NOT aliased)

    // ---- init ----
    for (int i = tid; i < NBAND * NPAIR; i += 512) (&bl[0][0])[i] = 0.f;

    // window (incl. 1/||w||): hanning(128)[n] = .5-.5cos(2*pi*n/127), ||w||^2=47.625
    const double PI = 3.14159265358979323846;
    const float  WI = (float)(1.0 / sqrt(47.625));
    const float wlo = (float)(0.5 - 0.5 * cos(2.0 * PI * (double)lane / 127.0)) * WI;
    const float whi = (float)(0.5 - 0.5 * cos(2.0 * PI * (double)(lane + 64) / 127.0)) * WI;

    // FFT twiddles (per lane, computed once); packed forms TW={r,i}, TWN={-i,r}
    const float PIF = 3.14159265358979f;
    float w128r, w128i;
    { float a = -2.f * PIF * (float)lane / 128.f; sincosf(a, &w128i, &w128r); }
    float t32r, t32i, t16r, t16i, t8r, t8i, t4r, t4i, t2r, t2i;
    { float a = (lane & 32) ? -2.f * PIF * (float)(lane & 31) / 64.f : 0.f; sincosf(a, &t32i, &t32r); }
    { float a = (lane & 16) ? -2.f * PIF * (float)(lane & 15) / 32.f : 0.f; sincosf(a, &t16i, &t16r); }
    { float a = (lane &  8) ? -2.f * PIF * (float)(lane &  7) / 16.f : 0.f; sincosf(a, &t8i,  &t8r ); }
    { float a = (lane &  4) ? -2.f * PIF * (float)(lane &  3) /  8.f : 0.f; sincosf(a, &t4i,  &t4r ); }
    { float a = (lane &  2) ? -2.f * PIF * (float)(lane &  1) /  4.f : 0.f; sincosf(a, &t2i,  &t2r ); }
    const v2f TWH  = { w128r,  w128i }, TWHN = { -w128i, w128r };
    const v2f TW32 = { t32r, t32i },    TW32N = { -t32i, t32r };
    const v2f TW16 = { t16r, t16i },    TW16N = { -t16i, t16r };
    const v2f TW8  = { t8r,  t8i  },    TW8N  = { -t8i,  t8r  };
    const v2f TW4  = { t4r,  t4i  },    TW4N  = { -t4i,  t4r  };
    const v2f TW2  = { t2r,  t2i  },    TW2N  = { -t2i,  t2r  };
    const v2f SG32 = { (lane & 32) ? -1.f : 1.f, (lane & 32) ? -1.f : 1.f };
    const v2f SG16 = { (lane & 16) ? -1.f : 1.f, (lane & 16) ? -1.f : 1.f };
    const v2f SG8  = { (lane &  8) ? -1.f : 1.f, (lane &  8) ? -1.f : 1.f };
    const v2f SG4  = { (lane &  4) ? -1.f : 1.f, (lane &  4) ? -1.f : 1.f };
    const v2f SG2  = { (lane &  2) ? -1.f : 1.f, (lane &  2) ? -1.f : 1.f };
    const v2f SG1  = { (lane &  1) ? -1.f : 1.f, (lane &  1) ? -1.f : 1.f };

    const int bp32 = 4 * (lane ^ 32);
    // untangle gather: U[k] lives at slot k&1, lane bitrev6(k>>1)
    const int La = (int)(__brev((unsigned)(f >> 1)) >> 26);
    const int Lb = (int)(__brev((unsigned)((128 - f) >> 1)) >> 26);
    const int pa = f & 1;

    v2f acc[17];
#pragma unroll
    for (int t = 0; t < 17; ++t) acc[t] = (v2f){0.f, 0.f};

    const float* xp0 = x + (size_t)(b * NCH + g) * T_LEN + (size_t)w * 128;
    const float* xp1 = xp0 + 8 * (size_t)T_LEN;

    __syncthreads();

    // ================= phase 1: STFT + CSD (R14 verbatim) =================
    for (int s = 0; s < 16; ++s) {
        v2f S0 = (v2f){ xp0[s * 32 + lane],      xp1[s * 32 + lane]      } * wlo;
        v2f S1 = (v2f){ xp0[s * 32 + lane + 64], xp1[s * 32 + lane + 64] } * whi;

        {   // stage span=64 (in-lane)
            v2f D = S0 - S1;
            S0 = S0 + S1;
            S1 = __builtin_elementwise_fma(D.xx, TWH, D.yy * TWHN);
        }
        BF2(S0, EX32, TW32, TW32N, SG32)
        BF2(S1, EX32, TW32, TW32N, SG32)
        BF2(S0, EX16, TW16, TW16N, SG16)
        BF2(S1, EX16, TW16, TW16N, SG16)
        BF2(S0, EX8,  TW8,  TW8N,  SG8)
        BF2(S1, EX8,  TW8,  TW8N,  SG8)
        BF2(S0, EX4,  TW4,  TW4N,  SG4)
        BF2(S1, EX4,  TW4,  TW4N,  SG4)
        BF2(S0, EX2,  TW2,  TW2N,  SG2)
        BF2(S1, EX2,  TW2,  TW2N,  SG2)
        {
            v2f p_; p_.x = EX1(S0.x); p_.y = EX1(S0.y);
            S0 = __builtin_elementwise_fma(SG1, S0, p_);
        }
        {
            v2f p_; p_.x = EX1(S1.x); p_.y = EX1(S1.y);
            S1 = __builtin_elementwise_fma(SG1, S1, p_);
        }

        // untangle via diag-padded per-wave scratch (wave-synchronous)
        scr[g][0][lane >> 4][lane & 15] = S0;
        scr[g][1][lane >> 4][lane & 15] = S1;
        v2f Ua = scr[g][pa][La >> 4][La & 15];
        v2f Ub = scr[g][pa][Lb >> 4][Lb & 15];
        v2f X0 = { 0.5f * (Ua.x + Ub.x), 0.5f * (Ua.y - Ub.y) };
        v2f X1 = { 0.5f * (Ua.y + Ub.y), 0.5f * (Ub.x - Ua.x) };

        // ping-pong exchange: single barrier per frame (R11-proven)
        const int pp = s & 1;
        X2[pp][g][lane]     = X0;
        X2[pp][g + 8][lane] = X1;
        __syncthreads();

        v2f X[16];
#pragma unroll
        for (int c = 0; c < 16; ++c) X[c] = X2[pp][c][lane];
        switch (g) {
            case 0: acc_csd<0>(X, acc); break;
            case 1: acc_csd<1>(X, acc); break;
            case 2: acc_csd<2>(X, acc); break;
            case 3: acc_csd<3>(X, acc); break;
            case 4: acc_csd<4>(X, acc); break;
            case 5: acc_csd<5>(X, acc); break;
            case 6: acc_csd<6>(X, acc); break;
            default: acc_csd<7>(X, acc); break;
        }
    }

    // ---- band reduction into bl ----
    const int kband = (lane < 6) ? 0 : (lane < 12) ? 1 : (lane < 19) ? 2
                    : (lane < 32) ? 3 : (lane < 48) ? 4 : 5;
#pragma unroll
    for (int t = 0; t < 17; ++t) {
        float vv = fmaf(acc[t].x, acc[t].x, acc[t].y * acc[t].y);
        atomicAdd(&bl[kband][g + 8 * t], vv);
    }
    __syncthreads();   // bl complete; X2/scr dead -> phase 2 may alias

    // ================= phase 2: eig + log recompose (waves 0-5) ===========
    if (g < 6) {
        const int jp = lane >> 3;   // pair 0..7
        const int n2 = lane & 7;    // column-pair 0..7

        // A init from bl (pair-index inverse), scale 1/(256*cnt); VT = I
        const float cnt = (g <= 1) ? 6.f : (g == 2) ? 7.f : (g == 3) ? 13.f : 16.f;
        const float rsg = 1.f / (256.f * cnt);
#pragma unroll
        for (int it = 0; it < 4; ++it) {
            int i = lane + it * 64, r = i >> 4, c = i & 15;
            int mn = r < c ? r : c, mx = r < c ? c : r;
            int p = (mn * (33 - mn)) / 2 + (mx - mn);
            A_[g][r][c]  = bl[g][p] * rsg;
            VT_[g][r][c] = (r == c) ? 1.f : 0.f;
        }
        // wave-synchronous from here: no barriers (R5/R14-proven structure)

        for (int sweep = 0; sweep < 4; ++sweep) {
            for (int rr = 0; rr < 15; ++rr) {
                int p, q; tourney(rr, jp, p, q);
                // phase A: rotation params + DT = A*J (stored transposed)
                float app = A_[g][p][p], aqq = A_[g][q][q], apq = A_[g][p][q];
                float c_ = 1.f, s_ = 0.f;
                if (apq != 0.f) {
                    float tau = (aqq - app) / (2.f * apq);
                    float t   = copysignf(1.f, tau) / (fabsf(tau) + sqrtf(1.f + tau * tau));
                    c_ = 1.f / sqrtf(1.f + t * t);
                    s_ = t * c_;
                }
                float2 ap = *(const float2*)&A_[g][p][2 * n2];
                float2 aq = *(const float2*)&A_[g][q][2 * n2];
                DT_[g][2 * n2][p]     = c_ * ap.x - s_ * aq.x;
                DT_[g][2 * n2 + 1][p] = c_ * ap.y - s_ * aq.y;
                DT_[g][2 * n2][q]     = s_ * ap.x + c_ * aq.x;
                DT_[g][2 * n2 + 1][q] = s_ * ap.y + c_ * aq.y;

                // phase B: A' = J^T * DT ; VT' = J^T * VT
                float2 dp = *(const float2*)&DT_[g][p][2 * n2];
                float2 dq = *(const float2*)&DT_[g][q][2 * n2];
                *(float2*)&A_[g][p][2 * n2] = make_float2(c_ * dp.x - s_ * dq.x,
                                                          c_ * dp.y - s_ * dq.y);
                *(float2*)&A_[g][q][2 * n2] = make_float2(s_ * dp.x + c_ * dq.x,
                                                          s_ * dp.y + c_ * dq.y);
                float2 vp = *(const float2*)&VT_[g][p][2 * n2];
                float2 vq = *(const float2*)&VT_[g][q][2 * n2];
                *(float2*)&VT_[g][p][2 * n2] = make_float2(c_ * vp.x - s_ * vq.x,
                                                           c_ * vp.y - s_ * vq.y);
                *(float2*)&VT_[g][q][2 * n2] = make_float2(s_ * vp.x + c_ * vq.x,
                                                           s_ * vp.y + c_ * vq.y);
            }
        }

        if (lane < 16) {
            float l = logf(A_[g][lane][lane]);
            if (isnan(l) || isinf(l)) l = 0.f;   // nan_to_num(nan=0, neginf=0)
            lv_[g][lane] = l;
        }

        // out[b][k][c][d][w] = sum_e VT[e][c] * lv[e] * VT[e][d]
        float* ob = out + (size_t)(b * NBAND + g) * 256 * NWIN;
#pragma unroll
        for (int it = 0; it < 4; ++it) {
            int i = lane + it * 64, c = i >> 4, d = i & 15;
            float sum = 0.f;
#pragma unroll
            for (int e = 0; e < 16; ++e) sum = fmaf(VT_[g][e][c] * lv_[g][e], VT_[g][e][d], sum);
            ob[(size_t)i * NWIN + w] = sum;
        }
    }
}

// ---------------------------------------------------------------------------
extern "C" void kernel_launch(void* const* d_in, const int* in_sizes, int n_in,
                              void* d_out, int out_size, void* d_ws, size_t ws_size,
                              hipStream_t stream)
{
    const float* x   = (const float*)d_in[0];
    float*       out = (float*)d_out;
    (void)d_ws; (void)ws_size;

    dim3 g1(NWIN, NB), b1(512);
    hipLaunchKernelGGL(csd_eig_kernel, g1, b1, 0, stream, x, out);
}

// Round 19
// 356.868 us; speedup vs baseline: 4.3255x; 1.1872x over previous
//
#include <hip/hip_runtime.h>
#include <math.h>

#define T_LEN 32768
#define NCH   16
#define NB    8
#define NWIN  252
#define NBAND 6
#define NPAIR 136

typedef float v2f __attribute__((ext_vector_type(2)));

// compile-time upper-triangle pair table (p -> (c,d))
struct PairTab { int c[NPAIR]; int d[NPAIR]; };
constexpr PairTab mkpairs() {
    PairTab P{}; int p = 0;
    for (int c = 0; c < 16; ++c)
        for (int d = c; d < 16; ++d) { P.c[p] = c; P.d[p] = d; ++p; }
    return P;
}
constexpr PairTab PT = mkpairs();

// CSD accumulate for wave-group G: pairs {G, G+8, ..., G+128} (17 pairs).
template<int G>
__device__ __forceinline__ void acc_csd(const v2f* __restrict__ X,
                                        v2f* __restrict__ acc)
{
#pragma unroll
    for (int t = 0; t < 17; ++t) {
        const int c = PT.c[G + 8 * t];
        const int d = PT.d[G + 8 * t];
        v2f Xc = X[c], Xd = X[d];
        acc[t] = __builtin_elementwise_fma(Xc, Xd.xx, acc[t]);
        acc[t] = __builtin_elementwise_fma((v2f){Xc.y, -Xc.x}, Xd.yy, acc[t]);
    }
}

// cross-lane exchange helpers (R4/R11/R14-proven set only)
#define SWZ(v, imm)  __int_as_float(__builtin_amdgcn_ds_swizzle(__float_as_int(v), (imm)))
#define DPPQ(v, ctl) __int_as_float(__builtin_amdgcn_mov_dpp(__float_as_int(v), (ctl), 0xF, 0xF, true))

// packed radix-2 DIF butterfly: v = {re, im}; partner p via EX per component.
__device__ __forceinline__ void bfv(v2f& v, v2f p, v2f tw, v2f twn, v2f sg)
{
    v2f t = __builtin_elementwise_fma(sg, v, p);
    v = __builtin_elementwise_fma(t.xx, tw, t.yy * twn);
}
#define BF2(v, EX, TW, TWN, SG) \
    { v2f p_; p_.x = EX(v.x); p_.y = EX(v.y); bfv(v, p_, TW, TWN, SG); }

// ---------------------------------------------------------------------------
// Kernel 1: fused STFT + CSD + band averaging. One 512-thread block per (b,w).
// R11 structure (single-barrier ping-pong, VGPR=64) + R14 diag-padded scr.
// [R14-proven, 237us, verbatim]
// ---------------------------------------------------------------------------
__global__ __launch_bounds__(512, 2) void csd_band_kernel(const float* __restrict__ x,
                                                          float* __restrict__ band)
{
    const int w    = blockIdx.x;
    const int b    = blockIdx.y;
    const int tid  = threadIdx.x;
    const int lane = tid & 63;
    const int g    = tid >> 6;     // wave id 0..7
    const int f    = lane + 1;     // this lane's output bin (1..64)

    __shared__ v2f  X2[2][NCH][64];     // ping-pong STFT exchange (16 KB)
    __shared__ v2f  scr[8][2][4][17];   // diag-padded untangle scratch (8.5 KB)
    __shared__ float bl[NBAND][NPAIR];  // band |csd|^2 sums
    __shared__ unsigned char pc_[NPAIR], pd_[NPAIR];

    // ---- init ----
    for (int i = tid; i < NBAND * NPAIR; i += 512) (&bl[0][0])[i] = 0.f;
    if (tid < NPAIR) {
        int rem = tid, c = 0;
        while (rem >= 16 - c) { rem -= 16 - c; ++c; }
        pc_[tid] = (unsigned char)c; pd_[tid] = (unsigned char)(c + rem);
    }

    // window (incl. 1/||w||): hanning(128)[n] = .5-.5cos(2*pi*n/127), ||w||^2=47.625
    const double PI = 3.14159265358979323846;
    const float  WI = (float)(1.0 / sqrt(47.625));
    const float wlo = (float)(0.5 - 0.5 * cos(2.0 * PI * (double)lane / 127.0)) * WI;
    const float whi = (float)(0.5 - 0.5 * cos(2.0 * PI * (double)(lane + 64) / 127.0)) * WI;

    // FFT twiddles (per lane, computed once); packed forms TW={r,i}, TWN={-i,r}
    const float PIF = 3.14159265358979f;
    float w128r, w128i;
    { float a = -2.f * PIF * (float)lane / 128.f; sincosf(a, &w128i, &w128r); }
    float t32r, t32i, t16r, t16i, t8r, t8i, t4r, t4i, t2r, t2i;
    { float a = (lane & 32) ? -2.f * PIF * (float)(lane & 31) / 64.f : 0.f; sincosf(a, &t32i, &t32r); }
    { float a = (lane & 16) ? -2.f * PIF * (float)(lane & 15) / 32.f : 0.f; sincosf(a, &t16i, &t16r); }
    { float a = (lane &  8) ? -2.f * PIF * (float)(lane &  7) / 16.f : 0.f; sincosf(a, &t8i,  &t8r ); }
    { float a = (lane &  4) ? -2.f * PIF * (float)(lane &  3) /  8.f : 0.f; sincosf(a, &t4i,  &t4r ); }
    { float a = (lane &  2) ? -2.f * PIF * (float)(lane &  1) /  4.f : 0.f; sincosf(a, &t2i,  &t2r ); }
    const v2f TWH  = { w128r,  w128i }, TWHN = { -w128i, w128r };
    const v2f TW32 = { t32r, t32i },    TW32N = { -t32i, t32r };
    const v2f TW16 = { t16r, t16i },    TW16N = { -t16i, t16r };
    const v2f TW8  = { t8r,  t8i  },    TW8N  = { -t8i,  t8r  };
    const v2f TW4  = { t4r,  t4i  },    TW4N  = { -t4i,  t4r  };
    const v2f TW2  = { t2r,  t2i  },    TW2N  = { -t2i,  t2r  };
    const v2f SG32 = { (lane & 32) ? -1.f : 1.f, (lane & 32) ? -1.f : 1.f };
    const v2f SG16 = { (lane & 16) ? -1.f : 1.f, (lane & 16) ? -1.f : 1.f };
    const v2f SG8  = { (lane &  8) ? -1.f : 1.f, (lane &  8) ? -1.f : 1.f };
    const v2f SG4  = { (lane &  4) ? -1.f : 1.f, (lane &  4) ? -1.f : 1.f };
    const v2f SG2  = { (lane &  2) ? -1.f : 1.f, (lane &  2) ? -1.f : 1.f };
    const v2f SG1  = { (lane &  1) ? -1.f : 1.f, (lane &  1) ? -1.f : 1.f };

    const int bp32 = 4 * (lane ^ 32);
    // untangle gather: U[k] lives at slot k&1, lane bitrev6(k>>1)
    const int La = (int)(__brev((unsigned)(f >> 1)) >> 26);
    const int Lb = (int)(__brev((unsigned)((128 - f) >> 1)) >> 26);
    const int pa = f & 1;

    v2f acc[17];
#pragma unroll
    for (int t = 0; t < 17; ++t) acc[t] = (v2f){0.f, 0.f};

    const float* xp0 = x + (size_t)(b * NCH + g) * T_LEN + (size_t)w * 128;
    const float* xp1 = xp0 + 8 * (size_t)T_LEN;

    __syncthreads();

    for (int s = 0; s < 16; ++s) {
        // ---- load + window + pack: u = xw_g + i*xw_{g+8}
        v2f S0 = (v2f){ xp0[s * 32 + lane],      xp1[s * 32 + lane]      } * wlo;
        v2f S1 = (v2f){ xp0[s * 32 + lane + 64], xp1[s * 32 + lane + 64] } * whi;

        // ---- stage span=64 (in-lane): S0=a+b, S1=(a-b)*W128^lane
        {
            v2f D = S0 - S1;
            S0 = S0 + S1;
            S1 = __builtin_elementwise_fma(D.xx, TWH, D.yy * TWHN);
        }
#define EX32(v) __int_as_float(__builtin_amdgcn_ds_bpermute(bp32, __float_as_int(v)))
#define EX16(v) SWZ(v, 0x401F)
#define EX8(v)  DPPQ(v, 0x128)   // row_ror:8 == lane^8 (R9/R10/R11/R14-verified)
#define EX4(v)  SWZ(v, 0x101F)
#define EX2(v)  DPPQ(v, 0x4E)    // quad_perm [2,3,0,1] = xor2
#define EX1(v)  DPPQ(v, 0xB1)    // quad_perm [1,0,3,2] = xor1
        BF2(S0, EX32, TW32, TW32N, SG32)
        BF2(S1, EX32, TW32, TW32N, SG32)
        BF2(S0, EX16, TW16, TW16N, SG16)
        BF2(S1, EX16, TW16, TW16N, SG16)
        BF2(S0, EX8,  TW8,  TW8N,  SG8)
        BF2(S1, EX8,  TW8,  TW8N,  SG8)
        BF2(S0, EX4,  TW4,  TW4N,  SG4)
        BF2(S1, EX4,  TW4,  TW4N,  SG4)
        BF2(S0, EX2,  TW2,  TW2N,  SG2)
        BF2(S1, EX2,  TW2,  TW2N,  SG2)
        {   // last stage span=1: no twiddle
            v2f p_; p_.x = EX1(S0.x); p_.y = EX1(S0.y);
            S0 = __builtin_elementwise_fma(SG1, S0, p_);
        }
        {
            v2f p_; p_.x = EX1(S1.x); p_.y = EX1(S1.y);
            S1 = __builtin_elementwise_fma(SG1, S1, p_);
        }

        // ---- untangle via diag-padded per-wave scratch (wave-synchronous)
        scr[g][0][lane >> 4][lane & 15] = S0;
        scr[g][1][lane >> 4][lane & 15] = S1;
        v2f Ua = scr[g][pa][La >> 4][La & 15];   // U[f]
        v2f Ub = scr[g][pa][Lb >> 4][Lb & 15];   // U[128-f]
        v2f X0 = { 0.5f * (Ua.x + Ub.x), 0.5f * (Ua.y - Ub.y) };
        v2f X1 = { 0.5f * (Ua.y + Ub.y), 0.5f * (Ub.x - Ua.x) };

        // ---- ping-pong exchange: single barrier per frame (R11-proven)
        const int pp = s & 1;
        X2[pp][g][lane]     = X0;
        X2[pp][g + 8][lane] = X1;
        __syncthreads();

        // ---- CSD accumulate (packed registers) ----
        v2f X[16];
#pragma unroll
        for (int c = 0; c < 16; ++c) X[c] = X2[pp][c][lane];
        switch (g) {
            case 0: acc_csd<0>(X, acc); break;
            case 1: acc_csd<1>(X, acc); break;
            case 2: acc_csd<2>(X, acc); break;
            case 3: acc_csd<3>(X, acc); break;
            case 4: acc_csd<4>(X, acc); break;
            case 5: acc_csd<5>(X, acc); break;
            case 6: acc_csd<6>(X, acc); break;
            default: acc_csd<7>(X, acc); break;
        }
    }

    // ---- band reduction ----
    const int kband = (lane < 6) ? 0 : (lane < 12) ? 1 : (lane < 19) ? 2
                    : (lane < 32) ? 3 : (lane < 48) ? 4 : 5;
#pragma unroll
    for (int t = 0; t < 17; ++t) {
        float vv = fmaf(acc[t].x, acc[t].x, acc[t].y * acc[t].y);
        atomicAdd(&bl[kband][g + 8 * t], vv);
    }
    __syncthreads();

    const float rs[NBAND] = { 1.f/(256.f*6.f), 1.f/(256.f*6.f), 1.f/(256.f*7.f),
                              1.f/(256.f*13.f), 1.f/(256.f*16.f), 1.f/(256.f*16.f) };
    float* bb = band + (size_t)(b * NWIN + w) * (NBAND * 256);
    for (int i = tid; i < NBAND * NPAIR; i += 512) {
        int k = i / NPAIR, p = i - k * NPAIR;
        int c = pc_[p], d = pd_[p];
        float val = bl[k][p] * rs[k];
        bb[k * 256 + c * 16 + d] = val;
        bb[k * 256 + d * 16 + c] = val;
    }
}

// ---------------------------------------------------------------------------
// Kernel 2: 16x16 symmetric eigendecomposition, fp32 parallel Jacobi
// (tournament ordering). 8 matrices per 512-thread block, one wave each,
// fully wave-synchronous: zero barriers. [R5/R14-proven] + convergence-gated
// 4th sweep: after 3 sweeps, skip sweep 4 if max|offdiag| < 1e-6*max|diag|
// (skipped matrices contribute <=1e-6 relative error; others still get it).
// ---------------------------------------------------------------------------
__device__ __forceinline__ void tourney(int rr, int j, int& p, int& q)
{
    if (j == 0) { p = 15; q = rr; }
    else { p = (rr + j) % 15; q = (rr + 15 - j) % 15; }
    if (p > q) { int t_ = p; p = q; q = t_; }
}

__device__ __forceinline__ void jacobi_sweep(float (*A)[18], float (*DT)[18],
                                             float (*VT)[18], int jp, int n2)
{
    for (int rr = 0; rr < 15; ++rr) {
        int p, q; tourney(rr, jp, p, q);
        // phase A: rotation params + DT = A*J (stored transposed)
        float app = A[p][p], aqq = A[q][q], apq = A[p][q];
        float c_ = 1.f, s_ = 0.f;
        if (apq != 0.f) {
            float tau = (aqq - app) / (2.f * apq);
            float t   = copysignf(1.f, tau) / (fabsf(tau) + sqrtf(1.f + tau * tau));
            c_ = 1.f / sqrtf(1.f + t * t);
            s_ = t * c_;
        }
        float2 ap = *(const float2*)&A[p][2 * n2];
        float2 aq = *(const float2*)&A[q][2 * n2];
        DT[2 * n2][p]     = c_ * ap.x - s_ * aq.x;
        DT[2 * n2 + 1][p] = c_ * ap.y - s_ * aq.y;
        DT[2 * n2][q]     = s_ * ap.x + c_ * aq.x;
        DT[2 * n2 + 1][q] = s_ * ap.y + c_ * aq.y;

        // phase B: A' = J^T * DT ; VT' = J^T * VT  (c_,s_ reused from regs)
        float2 dp = *(const float2*)&DT[p][2 * n2];
        float2 dq = *(const float2*)&DT[q][2 * n2];
        *(float2*)&A[p][2 * n2] = make_float2(c_ * dp.x - s_ * dq.x,
                                              c_ * dp.y - s_ * dq.y);
        *(float2*)&A[q][2 * n2] = make_float2(s_ * dp.x + c_ * dq.x,
                                              s_ * dp.y + c_ * dq.y);
        float2 vp = *(const float2*)&VT[p][2 * n2];
        float2 vq = *(const float2*)&VT[q][2 * n2];
        *(float2*)&VT[p][2 * n2] = make_float2(c_ * vp.x - s_ * vq.x,
                                               c_ * vp.y - s_ * vq.y);
        *(float2*)&VT[q][2 * n2] = make_float2(s_ * vp.x + c_ * vq.x,
                                               s_ * vp.y + c_ * vq.y);
    }
}

__global__ __launch_bounds__(512) void eig_log_kernel(const float* __restrict__ band,
                                                      float* __restrict__ out)
{
    const int tid  = threadIdx.x;
    const int g    = tid >> 6;          // matrix slot in block (one wave each)
    const int lane = tid & 63;
    const int m    = blockIdx.x * 8 + g;           // 0..12095
    const int k    = m % NBAND;
    const int bw   = m / NBAND;
    const int w    = bw % NWIN;
    const int b    = bw / NWIN;
    const int jp   = lane >> 3;   // pair 0..7
    const int n2   = lane & 7;    // column-pair 0..7

    __shared__ float A[8][16][18];
    __shared__ float DT[8][16][18];
    __shared__ float VT[8][16][18];
    __shared__ float lv[8][16];

    const float* M = band + ((size_t)(b * NWIN + w) * NBAND + k) * 256;
#pragma unroll
    for (int it = 0; it < 4; ++it) {
        int i = lane + it * 64, r = i >> 4, c = i & 15;
        A[g][r][c]  = M[i];
        VT[g][r][c] = (r == c) ? 1.f : 0.f;
    }
    // wave-synchronous from here on: no __syncthreads anywhere

    for (int sweep = 0; sweep < 3; ++sweep)
        jacobi_sweep(A[g], DT[g], VT[g], jp, n2);

    // convergence test: skip 4th sweep when already converged
    float off = 0.f, dg = 0.f;
#pragma unroll
    for (int it = 0; it < 4; ++it) {
        int i = lane + it * 64, r = i >> 4, c = i & 15;
        float v = fabsf(A[g][r][c]);
        if (r == c) dg = fmaxf(dg, v); else off = fmaxf(off, v);
    }
#pragma unroll
    for (int mm = 1; mm < 64; mm <<= 1) {
        off = fmaxf(off, __shfl_xor(off, mm, 64));
        dg  = fmaxf(dg,  __shfl_xor(dg,  mm, 64));
    }
    if (off > 1e-6f * dg)
        jacobi_sweep(A[g], DT[g], VT[g], jp, n2);

    if (lane < 16) {
        float l = logf(A[g][lane][lane]);
        if (isnan(l) || isinf(l)) l = 0.f;   // nan_to_num(nan=0, neginf=0)
        lv[g][lane] = l;
    }

    // out[b][k][c][d][w] = sum_e VT[e][c] * lv[e] * VT[e][d]
    float* ob = out + (size_t)(b * NBAND + k) * 256 * NWIN;
#pragma unroll
    for (int it = 0; it < 4; ++it) {
        int i = lane + it * 64, c = i >> 4, d = i & 15;
        float sum = 0.f;
#pragma unroll
        for (int e = 0; e < 16; ++e) sum = fmaf(VT[g][e][c] * lv[g][e], VT[g][e][d], sum);
        ob[(size_t)i * NWIN + w] = sum;
    }
}

// ---------------------------------------------------------------------------
extern "C" void kernel_launch(void* const* d_in, const int* in_sizes, int n_in,
                              void* d_out, int out_size, void* d_ws, size_t ws_size,
                              hipStream_t stream)
{
    const float* x    = (const float*)d_in[0];
    float*       out  = (float*)d_out;
    float*       band = (float*)d_ws;   // 8*252*6*256*4 = 12,386,304 bytes

    dim3 g1(NWIN, NB), b1(512);
    hipLaunchKernelGGL(csd_band_kernel, g1, b1, 0, stream, x, band);

    dim3 g2(NB * NWIN * NBAND / 8), b2(512);
    hipLaunchKernelGGL(eig_log_kernel, g2, b2, 0, stream, band, out);
}

// Round 20
// 356.698 us; speedup vs baseline: 4.3276x; 1.0005x over previous
//
#include <hip/hip_runtime.h>
#include <math.h>

#define T_LEN 32768
#define NCH   16
#define NB    8
#define NWIN  252
#define NBAND 6
#define NPAIR 136

typedef float v2f __attribute__((ext_vector_type(2)));

// compile-time upper-triangle pair table (p -> (c,d))
struct PairTab { int c[NPAIR]; int d[NPAIR]; };
constexpr PairTab mkpairs() {
    PairTab P{}; int p = 0;
    for (int c = 0; c < 16; ++c)
        for (int d = c; d < 16; ++d) { P.c[p] = c; P.d[p] = d; ++p; }
    return P;
}
constexpr PairTab PT = mkpairs();

// CSD accumulate for wave-group G: pairs {G, G+8, ..., G+128} (17 pairs).
template<int G>
__device__ __forceinline__ void acc_csd(const v2f* __restrict__ X,
                                        v2f* __restrict__ acc)
{
#pragma unroll
    for (int t = 0; t < 17; ++t) {
        const int c = PT.c[G + 8 * t];
        const int d = PT.d[G + 8 * t];
        v2f Xc = X[c], Xd = X[d];
        acc[t] = __builtin_elementwise_fma(Xc, Xd.xx, acc[t]);
        acc[t] = __builtin_elementwise_fma((v2f){Xc.y, -Xc.x}, Xd.yy, acc[t]);
    }
}

// cross-lane exchange helpers (R4/R11/R14-proven set only)
#define SWZ(v, imm)  __int_as_float(__builtin_amdgcn_ds_swizzle(__float_as_int(v), (imm)))
#define DPPQ(v, ctl) __int_as_float(__builtin_amdgcn_mov_dpp(__float_as_int(v), (ctl), 0xF, 0xF, true))

// packed radix-2 DIF butterfly: v = {re, im}; partner p via EX per component.
__device__ __forceinline__ void bfv(v2f& v, v2f p, v2f tw, v2f twn, v2f sg)
{
    v2f t = __builtin_elementwise_fma(sg, v, p);
    v = __builtin_elementwise_fma(t.xx, tw, t.yy * twn);
}
#define BF2(v, EX, TW, TWN, SG) \
    { v2f p_; p_.x = EX(v.x); p_.y = EX(v.y); bfv(v, p_, TW, TWN, SG); }

// ---------------------------------------------------------------------------
// Kernel 1: fused STFT + CSD + band averaging. One 512-thread block per (b,w).
// R11 structure (single-barrier ping-pong, VGPR=64) + R14 diag-padded scr.
// R20 probe: __launch_bounds__(512, 4) — request 4 waves/EU min (16/CU);
// VGPR must stay 64 (codegen unchanged), only scheduler residency may move.
// ---------------------------------------------------------------------------
__global__ __launch_bounds__(512, 4) void csd_band_kernel(const float* __restrict__ x,
                                                          float* __restrict__ band)
{
    const int w    = blockIdx.x;
    const int b    = blockIdx.y;
    const int tid  = threadIdx.x;
    const int lane = tid & 63;
    const int g    = tid >> 6;     // wave id 0..7
    const int f    = lane + 1;     // this lane's output bin (1..64)

    __shared__ v2f  X2[2][NCH][64];     // ping-pong STFT exchange (16 KB)
    __shared__ v2f  scr[8][2][4][17];   // diag-padded untangle scratch (8.5 KB)
    __shared__ float bl[NBAND][NPAIR];  // band |csd|^2 sums
    __shared__ unsigned char pc_[NPAIR], pd_[NPAIR];

    // ---- init ----
    for (int i = tid; i < NBAND * NPAIR; i += 512) (&bl[0][0])[i] = 0.f;
    if (tid < NPAIR) {
        int rem = tid, c = 0;
        while (rem >= 16 - c) { rem -= 16 - c; ++c; }
        pc_[tid] = (unsigned char)c; pd_[tid] = (unsigned char)(c + rem);
    }

    // window (incl. 1/||w||): hanning(128)[n] = .5-.5cos(2*pi*n/127), ||w||^2=47.625
    const double PI = 3.14159265358979323846;
    const float  WI = (float)(1.0 / sqrt(47.625));
    const float wlo = (float)(0.5 - 0.5 * cos(2.0 * PI * (double)lane / 127.0)) * WI;
    const float whi = (float)(0.5 - 0.5 * cos(2.0 * PI * (double)(lane + 64) / 127.0)) * WI;

    // FFT twiddles (per lane, computed once); packed forms TW={r,i}, TWN={-i,r}
    const float PIF = 3.14159265358979f;
    float w128r, w128i;
    { float a = -2.f * PIF * (float)lane / 128.f; sincosf(a, &w128i, &w128r); }
    float t32r, t32i, t16r, t16i, t8r, t8i, t4r, t4i, t2r, t2i;
    { float a = (lane & 32) ? -2.f * PIF * (float)(lane & 31) / 64.f : 0.f; sincosf(a, &t32i, &t32r); }
    { float a = (lane & 16) ? -2.f * PIF * (float)(lane & 15) / 32.f : 0.f; sincosf(a, &t16i, &t16r); }
    { float a = (lane &  8) ? -2.f * PIF * (float)(lane &  7) / 16.f : 0.f; sincosf(a, &t8i,  &t8r ); }
    { float a = (lane &  4) ? -2.f * PIF * (float)(lane &  3) /  8.f : 0.f; sincosf(a, &t4i,  &t4r ); }
    { float a = (lane &  2) ? -2.f * PIF * (float)(lane &  1) /  4.f : 0.f; sincosf(a, &t2i,  &t2r ); }
    const v2f TWH  = { w128r,  w128i }, TWHN = { -w128i, w128r };
    const v2f TW32 = { t32r, t32i },    TW32N = { -t32i, t32r };
    const v2f TW16 = { t16r, t16i },    TW16N = { -t16i, t16r };
    const v2f TW8  = { t8r,  t8i  },    TW8N  = { -t8i,  t8r  };
    const v2f TW4  = { t4r,  t4i  },    TW4N  = { -t4i,  t4r  };
    const v2f TW2  = { t2r,  t2i  },    TW2N  = { -t2i,  t2r  };
    const v2f SG32 = { (lane & 32) ? -1.f : 1.f, (lane & 32) ? -1.f : 1.f };
    const v2f SG16 = { (lane & 16) ? -1.f : 1.f, (lane & 16) ? -1.f : 1.f };
    const v2f SG8  = { (lane &  8) ? -1.f : 1.f, (lane &  8) ? -1.f : 1.f };
    const v2f SG4  = { (lane &  4) ? -1.f : 1.f, (lane &  4) ? -1.f : 1.f };
    const v2f SG2  = { (lane &  2) ? -1.f : 1.f, (lane &  2) ? -1.f : 1.f };
    const v2f SG1  = { (lane &  1) ? -1.f : 1.f, (lane &  1) ? -1.f : 1.f };

    const int bp32 = 4 * (lane ^ 32);
    // untangle gather: U[k] lives at slot k&1, lane bitrev6(k>>1)
    const int La = (int)(__brev((unsigned)(f >> 1)) >> 26);
    const int Lb = (int)(__brev((unsigned)((128 - f) >> 1)) >> 26);
    const int pa = f & 1;

    v2f acc[17];
#pragma unroll
    for (int t = 0; t < 17; ++t) acc[t] = (v2f){0.f, 0.f};

    const float* xp0 = x + (size_t)(b * NCH + g) * T_LEN + (size_t)w * 128;
    const float* xp1 = xp0 + 8 * (size_t)T_LEN;

    __syncthreads();

    for (int s = 0; s < 16; ++s) {
        // ---- load + window + pack: u = xw_g + i*xw_{g+8}
        v2f S0 = (v2f){ xp0[s * 32 + lane],      xp1[s * 32 + lane]      } * wlo;
        v2f S1 = (v2f){ xp0[s * 32 + lane + 64], xp1[s * 32 + lane + 64] } * whi;

        // ---- stage span=64 (in-lane): S0=a+b, S1=(a-b)*W128^lane
        {
            v2f D = S0 - S1;
            S0 = S0 + S1;
            S1 = __builtin_elementwise_fma(D.xx, TWH, D.yy * TWHN);
        }
#define EX32(v) __int_as_float(__builtin_amdgcn_ds_bpermute(bp32, __float_as_int(v)))
#define EX16(v) SWZ(v, 0x401F)
#define EX8(v)  DPPQ(v, 0x128)   // row_ror:8 == lane^8 (R9/R10/R11/R14-verified)
#define EX4(v)  SWZ(v, 0x101F)
#define EX2(v)  DPPQ(v, 0x4E)    // quad_perm [2,3,0,1] = xor2
#define EX1(v)  DPPQ(v, 0xB1)    // quad_perm [1,0,3,2] = xor1
        BF2(S0, EX32, TW32, TW32N, SG32)
        BF2(S1, EX32, TW32, TW32N, SG32)
        BF2(S0, EX16, TW16, TW16N, SG16)
        BF2(S1, EX16, TW16, TW16N, SG16)
        BF2(S0, EX8,  TW8,  TW8N,  SG8)
        BF2(S1, EX8,  TW8,  TW8N,  SG8)
        BF2(S0, EX4,  TW4,  TW4N,  SG4)
        BF2(S1, EX4,  TW4,  TW4N,  SG4)
        BF2(S0, EX2,  TW2,  TW2N,  SG2)
        BF2(S1, EX2,  TW2,  TW2N,  SG2)
        {   // last stage span=1: no twiddle
            v2f p_; p_.x = EX1(S0.x); p_.y = EX1(S0.y);
            S0 = __builtin_elementwise_fma(SG1, S0, p_);
        }
        {
            v2f p_; p_.x = EX1(S1.x); p_.y = EX1(S1.y);
            S1 = __builtin_elementwise_fma(SG1, S1, p_);
        }

        // ---- untangle via diag-padded per-wave scratch (wave-synchronous)
        scr[g][0][lane >> 4][lane & 15] = S0;
        scr[g][1][lane >> 4][lane & 15] = S1;
        v2f Ua = scr[g][pa][La >> 4][La & 15];   // U[f]
        v2f Ub = scr[g][pa][Lb >> 4][Lb & 15];   // U[128-f]
        v2f X0 = { 0.5f * (Ua.x + Ub.x), 0.5f * (Ua.y - Ub.y) };
        v2f X1 = { 0.5f * (Ua.y + Ub.y), 0.5f * (Ub.x - Ua.x) };

        // ---- ping-pong exchange: single barrier per frame (R11-proven)
        const int pp = s & 1;
        X2[pp][g][lane]     = X0;
        X2[pp][g + 8][lane] = X1;
        __syncthreads();

        // ---- CSD accumulate (packed registers) ----
        v2f X[16];
#pragma unroll
        for (int c = 0; c < 16; ++c) X[c] = X2[pp][c][lane];
        switch (g) {
            case 0: acc_csd<0>(X, acc); break;
            case 1: acc_csd<1>(X, acc); break;
            case 2: acc_csd<2>(X, acc); break;
            case 3: acc_csd<3>(X, acc); break;
            case 4: acc_csd<4>(X, acc); break;
            case 5: acc_csd<5>(X, acc); break;
            case 6: acc_csd<6>(X, acc); break;
            default: acc_csd<7>(X, acc); break;
        }
    }

    // ---- band reduction ----
    const int kband = (lane < 6) ? 0 : (lane < 12) ? 1 : (lane < 19) ? 2
                    : (lane < 32) ? 3 : (lane < 48) ? 4 : 5;
#pragma unroll
    for (int t = 0; t < 17; ++t) {
        float vv = fmaf(acc[t].x, acc[t].x, acc[t].y * acc[t].y);
        atomicAdd(&bl[kband][g + 8 * t], vv);
    }
    __syncthreads();

    const float rs[NBAND] = { 1.f/(256.f*6.f), 1.f/(256.f*6.f), 1.f/(256.f*7.f),
                              1.f/(256.f*13.f), 1.f/(256.f*16.f), 1.f/(256.f*16.f) };
    float* bb = band + (size_t)(b * NWIN + w) * (NBAND * 256);
    for (int i = tid; i < NBAND * NPAIR; i += 512) {
        int k = i / NPAIR, p = i - k * NPAIR;
        int c = pc_[p], d = pd_[p];
        float val = bl[k][p] * rs[k];
        bb[k * 256 + c * 16 + d] = val;
        bb[k * 256 + d * 16 + c] = val;
    }
}

// ---------------------------------------------------------------------------
// Kernel 2: 16x16 symmetric eigendecomposition, fp32 parallel Jacobi
// (tournament ordering). 8 matrices per 512-thread block, one wave each,
// fully wave-synchronous: zero barriers. [R5/R14-proven] + convergence-gated
// 4th sweep. R20 probe: __launch_bounds__(512, 4).
// ---------------------------------------------------------------------------
__device__ __forceinline__ void tourney(int rr, int j, int& p, int& q)
{
    if (j == 0) { p = 15; q = rr; }
    else { p = (rr + j) % 15; q = (rr + 15 - j) % 15; }
    if (p > q) { int t_ = p; p = q; q = t_; }
}

__device__ __forceinline__ void jacobi_sweep(float (*A)[18], float (*DT)[18],
                                             float (*VT)[18], int jp, int n2)
{
    for (int rr = 0; rr < 15; ++rr) {
        int p, q; tourney(rr, jp, p, q);
        // phase A: rotation params + DT = A*J (stored transposed)
        float app = A[p][p], aqq = A[q][q], apq = A[p][q];
        float c_ = 1.f, s_ = 0.f;
        if (apq != 0.f) {
            float tau = (aqq - app) / (2.f * apq);
            float t   = copysignf(1.f, tau) / (fabsf(tau) + sqrtf(1.f + tau * tau));
            c_ = 1.f / sqrtf(1.f + t * t);
            s_ = t * c_;
        }
        float2 ap = *(const float2*)&A[p][2 * n2];
        float2 aq = *(const float2*)&A[q][2 * n2];
        DT[2 * n2][p]     = c_ * ap.x - s_ * aq.x;
        DT[2 * n2 + 1][p] = c_ * ap.y - s_ * aq.y;
        DT[2 * n2][q]     = s_ * ap.x + c_ * aq.x;
        DT[2 * n2 + 1][q] = s_ * ap.y + c_ * aq.y;

        // phase B: A' = J^T * DT ; VT' = J^T * VT  (c_,s_ reused from regs)
        float2 dp = *(const float2*)&DT[p][2 * n2];
        float2 dq = *(const float2*)&DT[q][2 * n2];
        *(float2*)&A[p][2 * n2] = make_float2(c_ * dp.x - s_ * dq.x,
                                              c_ * dp.y - s_ * dq.y);
        *(float2*)&A[q][2 * n2] = make_float2(s_ * dp.x + c_ * dq.x,
                                              s_ * dp.y + c_ * dq.y);
        float2 vp = *(const float2*)&VT[p][2 * n2];
        float2 vq = *(const float2*)&VT[q][2 * n2];
        *(float2*)&VT[p][2 * n2] = make_float2(c_ * vp.x - s_ * vq.x,
                                               c_ * vp.y - s_ * vq.y);
        *(float2*)&VT[q][2 * n2] = make_float2(s_ * vp.x + c_ * vq.x,
                                               s_ * vp.y + c_ * vq.y);
    }
}

__global__ __launch_bounds__(512, 4) void eig_log_kernel(const float* __restrict__ band,
                                                         float* __restrict__ out)
{
    const int tid  = threadIdx.x;
    const int g    = tid >> 6;          // matrix slot in block (one wave each)
    const int lane = tid & 63;
    const int m    = blockIdx.x * 8 + g;           // 0..12095
    const int k    = m % NBAND;
    const int bw   = m / NBAND;
    const int w    = bw % NWIN;
    const int b    = bw / NWIN;
    const int jp   = lane >> 3;   // pair 0..7
    const int n2   = lane & 7;    // column-pair 0..7

    __shared__ float A[8][16][18];
    __shared__ float DT[8][16][18];
    __shared__ float VT[8][16][18];
    __shared__ float lv[8][16];

    const float* M = band + ((size_t)(b * NWIN + w) * NBAND + k) * 256;
#pragma unroll
    for (int it = 0; it < 4; ++it) {
        int i = lane + it * 64, r = i >> 4, c = i & 15;
        A[g][r][c]  = M[i];
        VT[g][r][c] = (r == c) ? 1.f : 0.f;
    }
    // wave-synchronous from here on: no __syncthreads anywhere

    for (int sweep = 0; sweep < 3; ++sweep)
        jacobi_sweep(A[g], DT[g], VT[g], jp, n2);

    // convergence test: skip 4th sweep when already converged
    float off = 0.f, dg = 0.f;
#pragma unroll
    for (int it = 0; it < 4; ++it) {
        int i = lane + it * 64, r = i >> 4, c = i & 15;
        float v = fabsf(A[g][r][c]);
        if (r == c) dg = fmaxf(dg, v); else off = fmaxf(off, v);
    }
#pragma unroll
    for (int mm = 1; mm < 64; mm <<= 1) {
        off = fmaxf(off, __shfl_xor(off, mm, 64));
        dg  = fmaxf(dg,  __shfl_xor(dg,  mm, 64));
    }
    if (off > 1e-6f * dg)
        jacobi_sweep(A[g], DT[g], VT[g], jp, n2);

    if (lane < 16) {
        float l = logf(A[g][lane][lane]);
        if (isnan(l) || isinf(l)) l = 0.f;   // nan_to_num(nan=0, neginf=0)
        lv[g][lane] = l;
    }

    // out[b][k][c][d][w] = sum_e VT[e][c] * lv[e] * VT[e][d]
    float* ob = out + (size_t)(b * NBAND + k) * 256 * NWIN;
#pragma unroll
    for (int it = 0; it < 4; ++it) {
        int i = lane + it * 64, c = i >> 4, d = i & 15;
        float sum = 0.f;
#pragma unroll
        for (int e = 0; e < 16; ++e) sum = fmaf(VT[g][e][c] * lv[g][e], VT[g][e][d], sum);
        ob[(size_t)i * NWIN + w] = sum;
    }
}

// ---------------------------------------------------------------------------
extern "C" void kernel_launch(void* const* d_in, const int* in_sizes, int n_in,
                              void* d_out, int out_size, void* d_ws, size_t ws_size,
                              hipStream_t stream)
{
    const float* x    = (const float*)d_in[0];
    float*       out  = (float*)d_out;
    float*       band = (float*)d_ws;   // 8*252*6*256*4 = 12,386,304 bytes

    dim3 g1(NWIN, NB), b1(512);
    hipLaunchKernelGGL(csd_band_kernel, g1, b1, 0, stream, x, band);

    dim3 g2(NB * NWIN * NBAND / 8), b2(512);
    hipLaunchKernelGGL(eig_log_kernel, g2, b2, 0, stream, band, out);
}

// Round 21
// 355.585 us; speedup vs baseline: 4.3412x; 1.0031x over previous
//
#include <hip/hip_runtime.h>
#include <math.h>

#define T_LEN 32768
#define NCH   16
#define NB    8
#define NWIN  252
#define NBAND 6
#define NPAIR 136

typedef float v2f __attribute__((ext_vector_type(2)));

// compile-time upper-triangle pair table (p -> (c,d))
struct PairTab { int c[NPAIR]; int d[NPAIR]; };
constexpr PairTab mkpairs() {
    PairTab P{}; int p = 0;
    for (int c = 0; c < 16; ++c)
        for (int d = c; d < 16; ++d) { P.c[p] = c; P.d[p] = d; ++p; }
    return P;
}
constexpr PairTab PT = mkpairs();

// CSD accumulate for wave-group G: pairs {G, G+8, ..., G+128} (17 pairs).
template<int G>
__device__ __forceinline__ void acc_csd(const v2f* __restrict__ X,
                                        v2f* __restrict__ acc)
{
#pragma unroll
    for (int t = 0; t < 17; ++t) {
        const int c = PT.c[G + 8 * t];
        const int d = PT.d[G + 8 * t];
        v2f Xc = X[c], Xd = X[d];
        acc[t] = __builtin_elementwise_fma(Xc, Xd.xx, acc[t]);
        acc[t] = __builtin_elementwise_fma((v2f){Xc.y, -Xc.x}, Xd.yy, acc[t]);
    }
}

// cross-lane exchange helpers (R4/R11/R14-proven set only)
#define SWZ(v, imm)  __int_as_float(__builtin_amdgcn_ds_swizzle(__float_as_int(v), (imm)))
#define DPPQ(v, ctl) __int_as_float(__builtin_amdgcn_mov_dpp(__float_as_int(v), (ctl), 0xF, 0xF, true))

// packed radix-2 DIF butterfly: v = {re, im}; partner p via EX per component.
__device__ __forceinline__ void bfv(v2f& v, v2f p, v2f tw, v2f twn, v2f sg)
{
    v2f t = __builtin_elementwise_fma(sg, v, p);
    v = __builtin_elementwise_fma(t.xx, tw, t.yy * twn);
}
#define BF2(v, EX, TW, TWN, SG) \
    { v2f p_; p_.x = EX(v.x); p_.y = EX(v.y); bfv(v, p_, TW, TWN, SG); }

// ---------------------------------------------------------------------------
// Kernel 1: fused STFT + CSD + band averaging. One 512-thread block per (b,w).
// R11 structure (single-barrier ping-pong, VGPR=64) + R14 diag-padded scr.
// R21: all-fp32 per-thread setup (no fp64 cos/sqrt libcalls in the prologue).
// ---------------------------------------------------------------------------
__global__ __launch_bounds__(512, 2) void csd_band_kernel(const float* __restrict__ x,
                                                          float* __restrict__ band)
{
    const int w    = blockIdx.x;
    const int b    = blockIdx.y;
    const int tid  = threadIdx.x;
    const int lane = tid & 63;
    const int g    = tid >> 6;     // wave id 0..7
    const int f    = lane + 1;     // this lane's output bin (1..64)

    __shared__ v2f  X2[2][NCH][64];     // ping-pong STFT exchange (16 KB)
    __shared__ v2f  scr[8][2][4][17];   // diag-padded untangle scratch (8.5 KB)
    __shared__ float bl[NBAND][NPAIR];  // band |csd|^2 sums
    __shared__ unsigned char pc_[NPAIR], pd_[NPAIR];

    // ---- init ----
    for (int i = tid; i < NBAND * NPAIR; i += 512) (&bl[0][0])[i] = 0.f;
    if (tid < NPAIR) {
        int rem = tid, c = 0;
        while (rem >= 16 - c) { rem -= 16 - c; ++c; }
        pc_[tid] = (unsigned char)c; pd_[tid] = (unsigned char)(c + rem);
    }

    // window (incl. 1/||w||): hanning(128)[n] = .5-.5cos(2*pi*n/127), ||w||^2=47.625
    // all-fp32: cosf accurate to ~1ulp, window err ~1e-7 << absmax floor.
    const float PIF = 3.14159265358979f;
    const float WI  = 1.f / sqrtf(47.625f);
    const float wlo = (0.5f - 0.5f * cosf(2.f * PIF * (float)lane / 127.f)) * WI;
    const float whi = (0.5f - 0.5f * cosf(2.f * PIF * (float)(lane + 64) / 127.f)) * WI;

    // FFT twiddles (per lane, computed once); packed forms TW={r,i}, TWN={-i,r}
    float w128r, w128i;
    { float a = -2.f * PIF * (float)lane / 128.f; sincosf(a, &w128i, &w128r); }
    float t32r, t32i, t16r, t16i, t8r, t8i, t4r, t4i, t2r, t2i;
    { float a = (lane & 32) ? -2.f * PIF * (float)(lane & 31) / 64.f : 0.f; sincosf(a, &t32i, &t32r); }
    { float a = (lane & 16) ? -2.f * PIF * (float)(lane & 15) / 32.f : 0.f; sincosf(a, &t16i, &t16r); }
    { float a = (lane &  8) ? -2.f * PIF * (float)(lane &  7) / 16.f : 0.f; sincosf(a, &t8i,  &t8r ); }
    { float a = (lane &  4) ? -2.f * PIF * (float)(lane &  3) /  8.f : 0.f; sincosf(a, &t4i,  &t4r ); }
    { float a = (lane &  2) ? -2.f * PIF * (float)(lane &  1) /  4.f : 0.f; sincosf(a, &t2i,  &t2r ); }
    const v2f TWH  = { w128r,  w128i }, TWHN = { -w128i, w128r };
    const v2f TW32 = { t32r, t32i },    TW32N = { -t32i, t32r };
    const v2f TW16 = { t16r, t16i },    TW16N = { -t16i, t16r };
    const v2f TW8  = { t8r,  t8i  },    TW8N  = { -t8i,  t8r  };
    const v2f TW4  = { t4r,  t4i  },    TW4N  = { -t4i,  t4r  };
    const v2f TW2  = { t2r,  t2i  },    TW2N  = { -t2i,  t2r  };
    const v2f SG32 = { (lane & 32) ? -1.f : 1.f, (lane & 32) ? -1.f : 1.f };
    const v2f SG16 = { (lane & 16) ? -1.f : 1.f, (lane & 16) ? -1.f : 1.f };
    const v2f SG8  = { (lane &  8) ? -1.f : 1.f, (lane &  8) ? -1.f : 1.f };
    const v2f SG4  = { (lane &  4) ? -1.f : 1.f, (lane &  4) ? -1.f : 1.f };
    const v2f SG2  = { (lane &  2) ? -1.f : 1.f, (lane &  2) ? -1.f : 1.f };
    const v2f SG1  = { (lane &  1) ? -1.f : 1.f, (lane &  1) ? -1.f : 1.f };

    const int bp32 = 4 * (lane ^ 32);
    // untangle gather: U[k] lives at slot k&1, lane bitrev6(k>>1)
    const int La = (int)(__brev((unsigned)(f >> 1)) >> 26);
    const int Lb = (int)(__brev((unsigned)((128 - f) >> 1)) >> 26);
    const int pa = f & 1;

    v2f acc[17];
#pragma unroll
    for (int t = 0; t < 17; ++t) acc[t] = (v2f){0.f, 0.f};

    const float* xp0 = x + (size_t)(b * NCH + g) * T_LEN + (size_t)w * 128;
    const float* xp1 = xp0 + 8 * (size_t)T_LEN;

    __syncthreads();

    for (int s = 0; s < 16; ++s) {
        // ---- load + window + pack: u = xw_g + i*xw_{g+8}
        v2f S0 = (v2f){ xp0[s * 32 + lane],      xp1[s * 32 + lane]      } * wlo;
        v2f S1 = (v2f){ xp0[s * 32 + lane + 64], xp1[s * 32 + lane + 64] } * whi;

        // ---- stage span=64 (in-lane): S0=a+b, S1=(a-b)*W128^lane
        {
            v2f D = S0 - S1;
            S0 = S0 + S1;
            S1 = __builtin_elementwise_fma(D.xx, TWH, D.yy * TWHN);
        }
#define EX32(v) __int_as_float(__builtin_amdgcn_ds_bpermute(bp32, __float_as_int(v)))
#define EX16(v) SWZ(v, 0x401F)
#define EX8(v)  DPPQ(v, 0x128)   // row_ror:8 == lane^8 (R9/R10/R11/R14-verified)
#define EX4(v)  SWZ(v, 0x101F)
#define EX2(v)  DPPQ(v, 0x4E)    // quad_perm [2,3,0,1] = xor2
#define EX1(v)  DPPQ(v, 0xB1)    // quad_perm [1,0,3,2] = xor1
        BF2(S0, EX32, TW32, TW32N, SG32)
        BF2(S1, EX32, TW32, TW32N, SG32)
        BF2(S0, EX16, TW16, TW16N, SG16)
        BF2(S1, EX16, TW16, TW16N, SG16)
        BF2(S0, EX8,  TW8,  TW8N,  SG8)
        BF2(S1, EX8,  TW8,  TW8N,  SG8)
        BF2(S0, EX4,  TW4,  TW4N,  SG4)
        BF2(S1, EX4,  TW4,  TW4N,  SG4)
        BF2(S0, EX2,  TW2,  TW2N,  SG2)
        BF2(S1, EX2,  TW2,  TW2N,  SG2)
        {   // last stage span=1: no twiddle
            v2f p_; p_.x = EX1(S0.x); p_.y = EX1(S0.y);
            S0 = __builtin_elementwise_fma(SG1, S0, p_);
        }
        {
            v2f p_; p_.x = EX1(S1.x); p_.y = EX1(S1.y);
            S1 = __builtin_elementwise_fma(SG1, S1, p_);
        }

        // ---- untangle via diag-padded per-wave scratch (wave-synchronous)
        scr[g][0][lane >> 4][lane & 15] = S0;
        scr[g][1][lane >> 4][lane & 15] = S1;
        v2f Ua = scr[g][pa][La >> 4][La & 15];   // U[f]
        v2f Ub = scr[g][pa][Lb >> 4][Lb & 15];   // U[128-f]
        v2f X0 = { 0.5f * (Ua.x + Ub.x), 0.5f * (Ua.y - Ub.y) };
        v2f X1 = { 0.5f * (Ua.y + Ub.y), 0.5f * (Ub.x - Ua.x) };

        // ---- ping-pong exchange: single barrier per frame (R11-proven)
        const int pp = s & 1;
        X2[pp][g][lane]     = X0;
        X2[pp][g + 8][lane] = X1;
        __syncthreads();

        // ---- CSD accumulate (packed registers) ----
        v2f X[16];
#pragma unroll
        for (int c = 0; c < 16; ++c) X[c] = X2[pp][c][lane];
        switch (g) {
            case 0: acc_csd<0>(X, acc); break;
            case 1: acc_csd<1>(X, acc); break;
            case 2: acc_csd<2>(X, acc); break;
            case 3: acc_csd<3>(X, acc); break;
            case 4: acc_csd<4>(X, acc); break;
            case 5: acc_csd<5>(X, acc); break;
            case 6: acc_csd<6>(X, acc); break;
            default: acc_csd<7>(X, acc); break;
        }
    }

    // ---- band reduction ----
    const int kband = (lane < 6) ? 0 : (lane < 12) ? 1 : (lane < 19) ? 2
                    : (lane < 32) ? 3 : (lane < 48) ? 4 : 5;
#pragma unroll
    for (int t = 0; t < 17; ++t) {
        float vv = fmaf(acc[t].x, acc[t].x, acc[t].y * acc[t].y);
        atomicAdd(&bl[kband][g + 8 * t], vv);
    }
    __syncthreads();

    const float rs[NBAND] = { 1.f/(256.f*6.f), 1.f/(256.f*6.f), 1.f/(256.f*7.f),
                              1.f/(256.f*13.f), 1.f/(256.f*16.f), 1.f/(256.f*16.f) };
    float* bb = band + (size_t)(b * NWIN + w) * (NBAND * 256);
    for (int i = tid; i < NBAND * NPAIR; i += 512) {
        int k = i / NPAIR, p = i - k * NPAIR;
        int c = pc_[p], d = pd_[p];
        float val = bl[k][p] * rs[k];
        bb[k * 256 + c * 16 + d] = val;
        bb[k * 256 + d * 16 + c] = val;
    }
}

// ---------------------------------------------------------------------------
// Kernel 2: 16x16 symmetric eigendecomposition, fp32 parallel Jacobi
// (tournament ordering). 8 matrices per 512-thread block, one wave each,
// fully wave-synchronous: zero barriers. [R5/R14-proven] + convergence-gated
// 4th sweep, threshold loosened to 2e-5 (R19's 1e-6 skipped ~nothing;
// 2e-5 perturbation -> log-output error <=~2e-3, under the 0.0056 floor).
// ---------------------------------------------------------------------------
__device__ __forceinline__ void tourney(int rr, int j, int& p, int& q)
{
    if (j == 0) { p = 15; q = rr; }
    else { p = (rr + j) % 15; q = (rr + 15 - j) % 15; }
    if (p > q) { int t_ = p; p = q; q = t_; }
}

__device__ __forceinline__ void jacobi_sweep(float (*A)[18], float (*DT)[18],
                                             float (*VT)[18], int jp, int n2)
{
    for (int rr = 0; rr < 15; ++rr) {
        int p, q; tourney(rr, jp, p, q);
        // phase A: rotation params + DT = A*J (stored transposed)
        float app = A[p][p], aqq = A[q][q], apq = A[p][q];
        float c_ = 1.f, s_ = 0.f;
        if (apq != 0.f) {
            float tau = (aqq - app) / (2.f * apq);
            float t   = copysignf(1.f, tau) / (fabsf(tau) + sqrtf(1.f + tau * tau));
            c_ = 1.f / sqrtf(1.f + t * t);
            s_ = t * c_;
        }
        float2 ap = *(const float2*)&A[p][2 * n2];
        float2 aq = *(const float2*)&A[q][2 * n2];
        DT[2 * n2][p]     = c_ * ap.x - s_ * aq.x;
        DT[2 * n2 + 1][p] = c_ * ap.y - s_ * aq.y;
        DT[2 * n2][q]     = s_ * ap.x + c_ * aq.x;
        DT[2 * n2 + 1][q] = s_ * ap.y + c_ * aq.y;

        // phase B: A' = J^T * DT ; VT' = J^T * VT  (c_,s_ reused from regs)
        float2 dp = *(const float2*)&DT[p][2 * n2];
        float2 dq = *(const float2*)&DT[q][2 * n2];
        *(float2*)&A[p][2 * n2] = make_float2(c_ * dp.x - s_ * dq.x,
                                              c_ * dp.y - s_ * dq.y);
        *(float2*)&A[q][2 * n2] = make_float2(s_ * dp.x + c_ * dq.x,
                                              s_ * dp.y + c_ * dq.y);
        float2 vp = *(const float2*)&VT[p][2 * n2];
        float2 vq = *(const float2*)&VT[q][2 * n2];
        *(float2*)&VT[p][2 * n2] = make_float2(c_ * vp.x - s_ * vq.x,
                                               c_ * vp.y - s_ * vq.y);
        *(float2*)&VT[q][2 * n2] = make_float2(s_ * vp.x + c_ * vq.x,
                                               s_ * vp.y + c_ * vq.y);
    }
}

__global__ __launch_bounds__(512) void eig_log_kernel(const float* __restrict__ band,
                                                      float* __restrict__ out)
{
    const int tid  = threadIdx.x;
    const int g    = tid >> 6;          // matrix slot in block (one wave each)
    const int lane = tid & 63;
    const int m    = blockIdx.x * 8 + g;           // 0..12095
    const int k    = m % NBAND;
    const int bw   = m / NBAND;
    const int w    = bw % NWIN;
    const int b    = bw / NWIN;
    const int jp   = lane >> 3;   // pair 0..7
    const int n2   = lane & 7;    // column-pair 0..7

    __shared__ float A[8][16][18];
    __shared__ float DT[8][16][18];
    __shared__ float VT[8][16][18];
    __shared__ float lv[8][16];

    const float* M = band + ((size_t)(b * NWIN + w) * NBAND + k) * 256;
#pragma unroll
    for (int it = 0; it < 4; ++it) {
        int i = lane + it * 64, r = i >> 4, c = i & 15;
        A[g][r][c]  = M[i];
        VT[g][r][c] = (r == c) ? 1.f : 0.f;
    }
    // wave-synchronous from here on: no __syncthreads anywhere

    for (int sweep = 0; sweep < 3; ++sweep)
        jacobi_sweep(A[g], DT[g], VT[g], jp, n2);

    // convergence test: skip 4th sweep when already converged
    float off = 0.f, dg = 0.f;
#pragma unroll
    for (int it = 0; it < 4; ++it) {
        int i = lane + it * 64, r = i >> 4, c = i & 15;
        float v = fabsf(A[g][r][c]);
        if (r == c) dg = fmaxf(dg, v); else off = fmaxf(off, v);
    }
#pragma unroll
    for (int mm = 1; mm < 64; mm <<= 1) {
        off = fmaxf(off, __shfl_xor(off, mm, 64));
        dg  = fmaxf(dg,  __shfl_xor(dg,  mm, 64));
    }
    if (off > 2e-5f * dg)
        jacobi_sweep(A[g], DT[g], VT[g], jp, n2);

    if (lane < 16) {
        float l = logf(A[g][lane][lane]);
        if (isnan(l) || isinf(l)) l = 0.f;   // nan_to_num(nan=0, neginf=0)
        lv[g][lane] = l;
    }

    // out[b][k][c][d][w] = sum_e VT[e][c] * lv[e] * VT[e][d]
    float* ob = out + (size_t)(b * NBAND + k) * 256 * NWIN;
#pragma unroll
    for (int it = 0; it < 4; ++it) {
        int i = lane + it * 64, c = i >> 4, d = i & 15;
        float sum = 0.f;
#pragma unroll
        for (int e = 0; e < 16; ++e) sum = fmaf(VT[g][e][c] * lv[g][e], VT[g][e][d], sum);
        ob[(size_t)i * NWIN + w] = sum;
    }
}

// ---------------------------------------------------------------------------
extern "C" void kernel_launch(void* const* d_in, const int* in_sizes, int n_in,
                              void* d_out, int out_size, void* d_ws, size_t ws_size,
                              hipStream_t stream)
{
    const float* x    = (const float*)d_in[0];
    float*       out  = (float*)d_out;
    float*       band = (float*)d_ws;   // 8*252*6*256*4 = 12,386,304 bytes

    dim3 g1(NWIN, NB), b1(512);
    hipLaunchKernelGGL(csd_band_kernel, g1, b1, 0, stream, x, band);

    dim3 g2(NB * NWIN * NBAND / 8), b2(512);
    hipLaunchKernelGGL(eig_log_kernel, g2, b2, 0, stream, band, out);
}

// Round 22
// 354.143 us; speedup vs baseline: 4.3588x; 1.0041x over previous
//
#include <hip/hip_runtime.h>
#include <math.h>

#define T_LEN 32768
#define NCH   16
#define NB    8
#define NWIN  252
#define NBAND 6
#define NPAIR 136

typedef float v2f __attribute__((ext_vector_type(2)));
typedef float v4f __attribute__((ext_vector_type(4)));

// compile-time upper-triangle pair table (p -> (c,d))
struct PairTab { int c[NPAIR]; int d[NPAIR]; };
constexpr PairTab mkpairs() {
    PairTab P{}; int p = 0;
    for (int c = 0; c < 16; ++c)
        for (int d = c; d < 16; ++d) { P.c[p] = c; P.d[p] = d; ++p; }
    return P;
}
constexpr PairTab PT = mkpairs();

// CSD accumulate for wave-group G: pairs {G, G+8, ..., G+128} (17 pairs).
template<int G>
__device__ __forceinline__ void acc_csd(const v2f* __restrict__ X,
                                        v2f* __restrict__ acc)
{
#pragma unroll
    for (int t = 0; t < 17; ++t) {
        const int c = PT.c[G + 8 * t];
        const int d = PT.d[G + 8 * t];
        v2f Xc = X[c], Xd = X[d];
        acc[t] = __builtin_elementwise_fma(Xc, Xd.xx, acc[t]);
        acc[t] = __builtin_elementwise_fma((v2f){Xc.y, -Xc.x}, Xd.yy, acc[t]);
    }
}

// cross-lane exchange helpers (R4/R11/R14-proven set only)
#define SWZ(v, imm)  __int_as_float(__builtin_amdgcn_ds_swizzle(__float_as_int(v), (imm)))
#define DPPQ(v, ctl) __int_as_float(__builtin_amdgcn_mov_dpp(__float_as_int(v), (ctl), 0xF, 0xF, true))

// packed radix-2 DIF butterfly: v = {re, im}; partner p via EX per component.
__device__ __forceinline__ void bfv(v2f& v, v2f p, v2f tw, v2f twn, v2f sg)
{
    v2f t = __builtin_elementwise_fma(sg, v, p);
    v = __builtin_elementwise_fma(t.xx, tw, t.yy * twn);
}
#define BF2(v, EX, TW, TWN, SG) \
    { v2f p_; p_.x = EX(v.x); p_.y = EX(v.y); bfv(v, p_, TW, TWN, SG); }

// ---------------------------------------------------------------------------
// Kernel 1: fused STFT + CSD + band averaging. One 512-thread block per (b,w).
// R11 structure (single-barrier ping-pong, VGPR=64) + R14 diag-padded scr +
// R21 all-fp32 setup. [236.5us proven, verbatim]
// ---------------------------------------------------------------------------
__global__ __launch_bounds__(512, 2) void csd_band_kernel(const float* __restrict__ x,
                                                          float* __restrict__ band)
{
    const int w    = blockIdx.x;
    const int b    = blockIdx.y;
    const int tid  = threadIdx.x;
    const int lane = tid & 63;
    const int g    = tid >> 6;     // wave id 0..7
    const int f    = lane + 1;     // this lane's output bin (1..64)

    __shared__ v2f  X2[2][NCH][64];     // ping-pong STFT exchange (16 KB)
    __shared__ v2f  scr[8][2][4][17];   // diag-padded untangle scratch (8.5 KB)
    __shared__ float bl[NBAND][NPAIR];  // band |csd|^2 sums
    __shared__ unsigned char pc_[NPAIR], pd_[NPAIR];

    // ---- init ----
    for (int i = tid; i < NBAND * NPAIR; i += 512) (&bl[0][0])[i] = 0.f;
    if (tid < NPAIR) {
        int rem = tid, c = 0;
        while (rem >= 16 - c) { rem -= 16 - c; ++c; }
        pc_[tid] = (unsigned char)c; pd_[tid] = (unsigned char)(c + rem);
    }

    // window (incl. 1/||w||): hanning(128)[n] = .5-.5cos(2*pi*n/127), ||w||^2=47.625
    const float PIF = 3.14159265358979f;
    const float WI  = 1.f / sqrtf(47.625f);
    const float wlo = (0.5f - 0.5f * cosf(2.f * PIF * (float)lane / 127.f)) * WI;
    const float whi = (0.5f - 0.5f * cosf(2.f * PIF * (float)(lane + 64) / 127.f)) * WI;

    // FFT twiddles (per lane, computed once); packed forms TW={r,i}, TWN={-i,r}
    float w128r, w128i;
    { float a = -2.f * PIF * (float)lane / 128.f; sincosf(a, &w128i, &w128r); }
    float t32r, t32i, t16r, t16i, t8r, t8i, t4r, t4i, t2r, t2i;
    { float a = (lane & 32) ? -2.f * PIF * (float)(lane & 31) / 64.f : 0.f; sincosf(a, &t32i, &t32r); }
    { float a = (lane & 16) ? -2.f * PIF * (float)(lane & 15) / 32.f : 0.f; sincosf(a, &t16i, &t16r); }
    { float a = (lane &  8) ? -2.f * PIF * (float)(lane &  7) / 16.f : 0.f; sincosf(a, &t8i,  &t8r ); }
    { float a = (lane &  4) ? -2.f * PIF * (float)(lane &  3) /  8.f : 0.f; sincosf(a, &t4i,  &t4r ); }
    { float a = (lane &  2) ? -2.f * PIF * (float)(lane &  1) /  4.f : 0.f; sincosf(a, &t2i,  &t2r ); }
    const v2f TWH  = { w128r,  w128i }, TWHN = { -w128i, w128r };
    const v2f TW32 = { t32r, t32i },    TW32N = { -t32i, t32r };
    const v2f TW16 = { t16r, t16i },    TW16N = { -t16i, t16r };
    const v2f TW8  = { t8r,  t8i  },    TW8N  = { -t8i,  t8r  };
    const v2f TW4  = { t4r,  t4i  },    TW4N  = { -t4i,  t4r  };
    const v2f TW2  = { t2r,  t2i  },    TW2N  = { -t2i,  t2r  };
    const v2f SG32 = { (lane & 32) ? -1.f : 1.f, (lane & 32) ? -1.f : 1.f };
    const v2f SG16 = { (lane & 16) ? -1.f : 1.f, (lane & 16) ? -1.f : 1.f };
    const v2f SG8  = { (lane &  8) ? -1.f : 1.f, (lane &  8) ? -1.f : 1.f };
    const v2f SG4  = { (lane &  4) ? -1.f : 1.f, (lane &  4) ? -1.f : 1.f };
    const v2f SG2  = { (lane &  2) ? -1.f : 1.f, (lane &  2) ? -1.f : 1.f };
    const v2f SG1  = { (lane &  1) ? -1.f : 1.f, (lane &  1) ? -1.f : 1.f };

    const int bp32 = 4 * (lane ^ 32);
    // untangle gather: U[k] lives at slot k&1, lane bitrev6(k>>1)
    const int La = (int)(__brev((unsigned)(f >> 1)) >> 26);
    const int Lb = (int)(__brev((unsigned)((128 - f) >> 1)) >> 26);
    const int pa = f & 1;

    v2f acc[17];
#pragma unroll
    for (int t = 0; t < 17; ++t) acc[t] = (v2f){0.f, 0.f};

    const float* xp0 = x + (size_t)(b * NCH + g) * T_LEN + (size_t)w * 128;
    const float* xp1 = xp0 + 8 * (size_t)T_LEN;

    __syncthreads();

    for (int s = 0; s < 16; ++s) {
        // ---- load + window + pack: u = xw_g + i*xw_{g+8}
        v2f S0 = (v2f){ xp0[s * 32 + lane],      xp1[s * 32 + lane]      } * wlo;
        v2f S1 = (v2f){ xp0[s * 32 + lane + 64], xp1[s * 32 + lane + 64] } * whi;

        // ---- stage span=64 (in-lane): S0=a+b, S1=(a-b)*W128^lane
        {
            v2f D = S0 - S1;
            S0 = S0 + S1;
            S1 = __builtin_elementwise_fma(D.xx, TWH, D.yy * TWHN);
        }
#define EX32(v) __int_as_float(__builtin_amdgcn_ds_bpermute(bp32, __float_as_int(v)))
#define EX16(v) SWZ(v, 0x401F)
#define EX8(v)  DPPQ(v, 0x128)   // row_ror:8 == lane^8 (R9/R10/R11/R14-verified)
#define EX4(v)  SWZ(v, 0x101F)
#define EX2(v)  DPPQ(v, 0x4E)    // quad_perm [2,3,0,1] = xor2
#define EX1(v)  DPPQ(v, 0xB1)    // quad_perm [1,0,3,2] = xor1
        BF2(S0, EX32, TW32, TW32N, SG32)
        BF2(S1, EX32, TW32, TW32N, SG32)
        BF2(S0, EX16, TW16, TW16N, SG16)
        BF2(S1, EX16, TW16, TW16N, SG16)
        BF2(S0, EX8,  TW8,  TW8N,  SG8)
        BF2(S1, EX8,  TW8,  TW8N,  SG8)
        BF2(S0, EX4,  TW4,  TW4N,  SG4)
        BF2(S1, EX4,  TW4,  TW4N,  SG4)
        BF2(S0, EX2,  TW2,  TW2N,  SG2)
        BF2(S1, EX2,  TW2,  TW2N,  SG2)
        {   // last stage span=1: no twiddle
            v2f p_; p_.x = EX1(S0.x); p_.y = EX1(S0.y);
            S0 = __builtin_elementwise_fma(SG1, S0, p_);
        }
        {
            v2f p_; p_.x = EX1(S1.x); p_.y = EX1(S1.y);
            S1 = __builtin_elementwise_fma(SG1, S1, p_);
        }

        // ---- untangle via diag-padded per-wave scratch (wave-synchronous)
        scr[g][0][lane >> 4][lane & 15] = S0;
        scr[g][1][lane >> 4][lane & 15] = S1;
        v2f Ua = scr[g][pa][La >> 4][La & 15];   // U[f]
        v2f Ub = scr[g][pa][Lb >> 4][Lb & 15];   // U[128-f]
        v2f X0 = { 0.5f * (Ua.x + Ub.x), 0.5f * (Ua.y - Ub.y) };
        v2f X1 = { 0.5f * (Ua.y + Ub.y), 0.5f * (Ub.x - Ua.x) };

        // ---- ping-pong exchange: single barrier per frame (R11-proven)
        const int pp = s & 1;
        X2[pp][g][lane]     = X0;
        X2[pp][g + 8][lane] = X1;
        __syncthreads();

        // ---- CSD accumulate (packed registers) ----
        v2f X[16];
#pragma unroll
        for (int c = 0; c < 16; ++c) X[c] = X2[pp][c][lane];
        switch (g) {
            case 0: acc_csd<0>(X, acc); break;
            case 1: acc_csd<1>(X, acc); break;
            case 2: acc_csd<2>(X, acc); break;
            case 3: acc_csd<3>(X, acc); break;
            case 4: acc_csd<4>(X, acc); break;
            case 5: acc_csd<5>(X, acc); break;
            case 6: acc_csd<6>(X, acc); break;
            default: acc_csd<7>(X, acc); break;
        }
    }

    // ---- band reduction ----
    const int kband = (lane < 6) ? 0 : (lane < 12) ? 1 : (lane < 19) ? 2
                    : (lane < 32) ? 3 : (lane < 48) ? 4 : 5;
#pragma unroll
    for (int t = 0; t < 17; ++t) {
        float vv = fmaf(acc[t].x, acc[t].x, acc[t].y * acc[t].y);
        atomicAdd(&bl[kband][g + 8 * t], vv);
    }
    __syncthreads();

    const float rs[NBAND] = { 1.f/(256.f*6.f), 1.f/(256.f*6.f), 1.f/(256.f*7.f),
                              1.f/(256.f*13.f), 1.f/(256.f*16.f), 1.f/(256.f*16.f) };
    float* bb = band + (size_t)(b * NWIN + w) * (NBAND * 256);
    for (int i = tid; i < NBAND * NPAIR; i += 512) {
        int k = i / NPAIR, p = i - k * NPAIR;
        int c = pc_[p], d = pd_[p];
        float val = bl[k][p] * rs[k];
        bb[k * 256 + c * 16 + d] = val;
        bb[k * 256 + d * 16 + c] = val;
    }
}

// ---------------------------------------------------------------------------
// Kernel 2: 16x16 symmetric eigendecomposition, fp32 parallel Jacobi
// (tournament ordering, 4 sweeps). R22: 32 LANES PER MATRIX (4 lanes x 8
// pair-groups, float4 column-quads), TWO matrices per wave, 16 per 512-thr
// block. Row accesses are b128; only the DT transpose-scatter stays b32.
// ~40% fewer DS instructions per matrix (eig is DS-issue-bound).
// Same rotation sequence/arithmetic as the proven 64-lane version.
// Fully wave-synchronous: zero barriers.
// ---------------------------------------------------------------------------
__device__ __forceinline__ void tourney(int rr, int j, int& p, int& q)
{
    if (j == 0) { p = 15; q = rr; }
    else { p = (rr + j) % 15; q = (rr + 15 - j) % 15; }
    if (p > q) { int t_ = p; p = q; q = t_; }
}

__global__ __launch_bounds__(512) void eig_log_kernel(const float* __restrict__ band,
                                                      float* __restrict__ out)
{
    const int tid  = threadIdx.x;
    const int half = tid >> 5;          // matrix slot in block, 0..15
    const int sub  = tid & 31;          // lane within matrix
    const int m    = blockIdx.x * 16 + half;       // 0..12095
    const int k    = m % NBAND;
    const int bw   = m / NBAND;
    const int w    = bw % NWIN;
    const int b    = bw / NWIN;
    const int jp   = sub >> 2;          // pair group 0..7
    const int n4   = sub & 3;           // float4 column-quad 0..3

    // row stride 5 quads (20 floats, odd quad-stride spreads banks)
    __shared__ v4f A4[16][16][5];
    __shared__ v4f D4[16][16][5];
    __shared__ v4f V4[16][16][5];
    __shared__ float lv[16][16];

    float* Af = (float*)&A4[half][0][0];   // A[r][c] at Af[r*20 + c]
    float* Df = (float*)&D4[half][0][0];
    float* Vf = (float*)&V4[half][0][0];

    const v4f* M4 = (const v4f*)(band + ((size_t)(b * NWIN + w) * NBAND + k) * 256);
#pragma unroll
    for (int it = 0; it < 2; ++it) {
        int t = sub + it * 32;          // quad id 0..63
        int r = t >> 2, n = t & 3;
        A4[half][r][n] = M4[t];
        V4[half][r][n] = (v4f){ (float)(r == 4 * n),     (float)(r == 4 * n + 1),
                                (float)(r == 4 * n + 2), (float)(r == 4 * n + 3) };
    }
    // wave-synchronous from here on: no __syncthreads anywhere

    for (int sweep = 0; sweep < 4; ++sweep) {
        for (int rr = 0; rr < 15; ++rr) {
            int p, q; tourney(rr, jp, p, q);
            // rotation params (scalar broadcast reads)
            float app = Af[p * 20 + p], aqq = Af[q * 20 + q], apq = Af[p * 20 + q];
            float c_ = 1.f, s_ = 0.f;
            if (apq != 0.f) {
                float tau = (aqq - app) / (2.f * apq);
                float t   = copysignf(1.f, tau) / (fabsf(tau) + sqrtf(1.f + tau * tau));
                c_ = 1.f / sqrtf(1.f + t * t);
                s_ = t * c_;
            }
            // phase A: DT = A*J stored transposed. Row reads b128, scatter b32.
            v4f Ap = A4[half][p][n4], Aq = A4[half][q][n4];
            v4f Wp = c_ * Ap - s_ * Aq;        // -> DT[4n4+j][p]
            v4f Wq = s_ * Ap + c_ * Aq;        // -> DT[4n4+j][q]
            Df[(4 * n4 + 0) * 20 + p] = Wp.x;
            Df[(4 * n4 + 1) * 20 + p] = Wp.y;
            Df[(4 * n4 + 2) * 20 + p] = Wp.z;
            Df[(4 * n4 + 3) * 20 + p] = Wp.w;
            Df[(4 * n4 + 0) * 20 + q] = Wq.x;
            Df[(4 * n4 + 1) * 20 + q] = Wq.y;
            Df[(4 * n4 + 2) * 20 + q] = Wq.z;
            Df[(4 * n4 + 3) * 20 + q] = Wq.w;

            // phase B: A' = J^T * DT ; VT' = J^T * VT  (all b128)
            v4f Dp = D4[half][p][n4], Dq = D4[half][q][n4];
            A4[half][p][n4] = c_ * Dp - s_ * Dq;
            A4[half][q][n4] = s_ * Dp + c_ * Dq;
            v4f Vp = V4[half][p][n4], Vq = V4[half][q][n4];
            V4[half][p][n4] = c_ * Vp - s_ * Vq;
            V4[half][q][n4] = s_ * Vp + c_ * Vq;
        }
    }

    if (sub < 16) {
        float l = logf(Af[sub * 20 + sub]);
        if (isnan(l) || isinf(l)) l = 0.f;   // nan_to_num(nan=0, neginf=0)
        lv[half][sub] = l;
    }

    // out[b][k][c][d][w] = sum_e VT[e][c] * lv[e] * VT[e][d]
    float* ob = out + (size_t)(b * NBAND + k) * 256 * NWIN;
#pragma unroll
    for (int it = 0; it < 8; ++it) {
        int i = sub + it * 32, c = i >> 4, d = i & 15;
        float sum = 0.f;
#pragma unroll
        for (int e = 0; e < 16; ++e)
            sum = fmaf(Vf[e * 20 + c] * lv[half][e], Vf[e * 20 + d], sum);
        ob[(size_t)i * NWIN + w] = sum;
    }
}

// ---------------------------------------------------------------------------
extern "C" void kernel_launch(void* const* d_in, const int* in_sizes, int n_in,
                              void* d_out, int out_size, void* d_ws, size_t ws_size,
                              hipStream_t stream)
{
    const float* x    = (const float*)d_in[0];
    float*       out  = (float*)d_out;
    float*       band = (float*)d_ws;   // 8*252*6*256*4 = 12,386,304 bytes

    dim3 g1(NWIN, NB), b1(512);
    hipLaunchKernelGGL(csd_band_kernel, g1, b1, 0, stream, x, band);

    dim3 g2(NB * NWIN * NBAND / 16), b2(512);
    hipLaunchKernelGGL(eig_log_kernel, g2, b2, 0, stream, band, out);
}